// Round 7
// baseline (511.979 us; speedup 1.0000x reference)
//
#include <hip/hip_runtime.h>
#include <hip/hip_bf16.h>
#include <cstdint>

// ---------------- problem constants ----------------
#define NB 32
#define NC 384
#define NT 16
#define NH 14
#define NW 14
#define HWI 196          // 14*14
#define HOW 6            // conv out H,W
#define HWO 36           // 6*6
#define C2 768
#define MCONV (NB*NT*HWO)   // 18432
#define KCONV 3456          // 384*9
#define TOPK 8
#define NSAMP 1000
#define OUT_TOPK_ELEMS (NB*NC*TOPK*HWI)  // 19267584
#define OUT_INDS_OFF   (2*OUT_TOPK_ELEMS) // 38535168
#define PELEMS (MCONV*NC)                 // 7077888 per partial

// ---------------- ws layout (bytes) ----------------
#define OFF_FHI  0ull
#define OFF_FLO  77070336ull
#define OFF_WHI  154140672ull
#define OFF_WLO  156794880ull
#define OFF_CONV 159449088ull
// region A overlays FHI after conv is done (written only post-conv):
#define OFF_SARR 0ull            // 512*384*4 = 786432
#define OFF_SQAR 786432ull
#define OFF_MXAR 1572864ull
#define OFF_MNAR 2359296ull
#define OFF_BNSC 3145728ull
#define OFF_BNSH 3147264ull
#define OFF_Y    3148800ull      // 512*768*4 = 1572864
#define OFF_X1   4721664ull
#define OFF_GM   6294528ull      // 49152
#define OFF_H1   6343680ull      // 786432
#define OFF_H2   7130112ull      // 393216
#define OFF_PCNT 7523328ull      // 32*8*256*4 = 262144

typedef __attribute__((ext_vector_type(4))) float f32x4;
typedef __attribute__((ext_vector_type(8))) short bf16x8;

__device__ __forceinline__ unsigned short f2bf(float f) {
  unsigned u = __float_as_uint(f);
  unsigned r = (u + 0x7FFFu + ((u >> 16) & 1u)) >> 16;  // RN-even
  return (unsigned short)r;
}
__device__ __forceinline__ float bf2f(unsigned short u) {
  return __uint_as_float(((unsigned)u) << 16);
}

__device__ __forceinline__ void gload_lds16(const void* gptr, void* lptr) {
  __builtin_amdgcn_global_load_lds(
      (const __attribute__((address_space(1))) unsigned int*)gptr,
      (__attribute__((address_space(3))) unsigned int*)lptr, 16, 0, 0);
}

// ---------------- 1) fused: frames -> (b,t,hw,c) bf16 hi/lo  AND  conv_w transpose ----------------
__global__ __launch_bounds__(256)
void split_all(const float* __restrict__ fr, const float* __restrict__ cw,
               unsigned short* __restrict__ fhi, unsigned short* __restrict__ flo,
               unsigned short* __restrict__ whi, unsigned short* __restrict__ wlo) {
  __shared__ char smem[64 * 197 * 4];
  int bid = blockIdx.x;
  if (bid < 3072) {
    unsigned int (*tile)[197] = (unsigned int (*)[197])smem;
    int cb = bid % 6, bt = bid / 6;
    int b = bt >> 4, t = bt & 15;
    const float* src = fr + (((size_t)b * NC + cb * 64) * NT + t) * HWI;
    for (int i = threadIdx.x; i < 64 * 49; i += 256) {
      int c = i / 49, q = i - c * 49;
      float4 v = *(const float4*)(src + (size_t)c * (NT * HWI) + q * 4);
      float vv[4] = {v.x, v.y, v.z, v.w};
#pragma unroll
      for (int u = 0; u < 4; ++u) {
        unsigned short h = f2bf(vv[u]);
        unsigned short l = f2bf(vv[u] - bf2f(h));
        tile[c][q * 4 + u] = ((unsigned)h << 16) | (unsigned)l;
      }
    }
    __syncthreads();
    size_t obase = ((size_t)bt * HWI) * NC + cb * 64;
    for (int i = threadIdx.x; i < 196 * 8; i += 256) {
      int hw = i >> 3, c8 = i & 7;
      bf16x8 vh, vl;
#pragma unroll
      for (int u = 0; u < 8; ++u) {
        unsigned p = tile[c8 * 8 + u][hw];
        vh[u] = (short)(p >> 16);
        vl[u] = (short)(p & 0xffff);
      }
      size_t o = obase + (size_t)hw * NC + c8 * 8;
      *(bf16x8*)(fhi + o) = vh;
      *(bf16x8*)(flo + o) = vl;
    }
  } else {
    float* t = (float*)smem;
    int co = bid - 3072;
    const float* src = cw + (size_t)co * KCONV;
    for (int i = threadIdx.x; i < KCONV / 4; i += 256)
      *(float4*)&t[i * 4] = *(const float4*)&src[i * 4];
    __syncthreads();
    unsigned short* oh = whi + (size_t)co * KCONV;
    unsigned short* ol = wlo + (size_t)co * KCONV;
    for (int i = threadIdx.x; i < KCONV; i += 256) {
      int c9 = i / NC, ci = i - c9 * NC;
      float v = t[ci * 9 + c9];
      unsigned short h = f2bf(v);
      oh[i] = h; ol[i] = f2bf(v - bf2f(h));
    }
  }
}

// ---------------- 3) conv implicit GEMM, split-bf16 3-product, split-K=4, swizzled LDS ----------------
// LDS swizzle verified conflict-free (R4: SQ_LDS_BANK_CONFLICT=0).
// XCD decode (T1): x=bid&7 is the HW round-robin XCD; bm = x*18 + (i%18), r = i/18.
// All 12 sharers (3 bn x 4 kz) of an A-tile land on one XCD and are co-resident.
__global__ __launch_bounds__(256, 4)
void conv_gemm(const unsigned short* __restrict__ fhi,
               const unsigned short* __restrict__ flo,
               const unsigned short* __restrict__ whi,
               const unsigned short* __restrict__ wlo,
               const float* __restrict__ conv_b,
               float* __restrict__ p0, float* __restrict__ p1,
               float* __restrict__ p2, float* __restrict__ p3) {
  __shared__ unsigned short sAhi[128 * 32], sAlo[128 * 32];
  __shared__ unsigned short sBhi[128 * 32], sBlo[128 * 32];
  const int tid = threadIdx.x;
  const int lane = tid & 63;
  const int wv = tid >> 6;
  const int bid = blockIdx.x;
  const int x  = bid & 7;
  const int i_ = bid >> 3;         // 0..215
  const int bm = x * 18 + (i_ % 18);
  const int r  = i_ / 18;          // 0..11
  const int bn = r % 3;
  const int kz = r / 3;            // 0..3

  int aoff[2], boff[2];
#pragma unroll
  for (int j = 0; j < 2; ++j) {
    int l = (wv * 2 + j) * 64 + lane;
    int row = l >> 2;
    int chunk = (l & 3) ^ ((l >> 3) & 3);   // swizzled source chunk
    int m = bm * 128 + row;
    int wo = m % 6; int tmp = m / 6;
    int ho = tmp % 6; tmp /= 6;     // tmp = b*16+t
    aoff[j] = ((tmp * HWI) + (2 * ho) * NW + 2 * wo) * NC + chunk * 8;
    int co = bn * 128 + row;
    boff[j] = co * KCONV + chunk * 8;
  }

  f32x4 acc[4][4];
#pragma unroll
  for (int i = 0; i < 4; ++i)
#pragma unroll
    for (int j = 0; j < 4; ++j) acc[i][j] = (f32x4){0.f, 0.f, 0.f, 0.f};

  const int wrow = (wv >> 1) * 64;
  const int wcol = (wv & 1) * 64;
  const int fr_row = lane & 15;
  const int slot8 = (((lane >> 4) ^ ((fr_row >> 1) & 3))) * 8;

  int c9  = (kz * 27) / 12;
  int rem = (kz * 27) % 12;
  for (int s = 0; s < 27; ++s) {
    int kh = c9 / 3, kw = c9 - kh * 3;
    int soffA = (kh * NW + kw) * NC + rem * 32;
    int soffB = c9 * NC + rem * 32;
#pragma unroll
    for (int j = 0; j < 2; ++j) {
      char* ldsA  = (char*)sAhi + (wv * 2 + j) * 1024;
      char* ldsAl = (char*)sAlo + (wv * 2 + j) * 1024;
      char* ldsB  = (char*)sBhi + (wv * 2 + j) * 1024;
      char* ldsBl = (char*)sBlo + (wv * 2 + j) * 1024;
      gload_lds16(fhi + aoff[j] + soffA, ldsA);
      gload_lds16(flo + aoff[j] + soffA, ldsAl);
      gload_lds16(whi + boff[j] + soffB, ldsB);
      gload_lds16(wlo + boff[j] + soffB, ldsBl);
    }
    __syncthreads();
    bf16x8 ah[4], al[4], bh[4], bl[4];
#pragma unroll
    for (int m = 0; m < 4; ++m) {
      int rr = wrow + m * 16 + fr_row;
      ah[m] = *(const bf16x8*)&sAhi[rr * 32 + slot8];
      al[m] = *(const bf16x8*)&sAlo[rr * 32 + slot8];
    }
#pragma unroll
    for (int n = 0; n < 4; ++n) {
      int rr = wcol + n * 16 + fr_row;
      bh[n] = *(const bf16x8*)&sBhi[rr * 32 + slot8];
      bl[n] = *(const bf16x8*)&sBlo[rr * 32 + slot8];
    }
#pragma unroll
    for (int m = 0; m < 4; ++m)
#pragma unroll
      for (int n = 0; n < 4; ++n) {
        acc[m][n] = __builtin_amdgcn_mfma_f32_16x16x32_bf16(ah[m], bh[n], acc[m][n], 0, 0, 0);
        acc[m][n] = __builtin_amdgcn_mfma_f32_16x16x32_bf16(ah[m], bl[n], acc[m][n], 0, 0, 0);
        acc[m][n] = __builtin_amdgcn_mfma_f32_16x16x32_bf16(al[m], bh[n], acc[m][n], 0, 0, 0);
      }
    __syncthreads();
    if (++rem == 12) { rem = 0; ++c9; }
  }

  float* dst = (kz == 0) ? p0 : (kz == 1) ? p1 : (kz == 2) ? p2 : p3;
#pragma unroll
  for (int m = 0; m < 4; ++m)
#pragma unroll
    for (int n = 0; n < 4; ++n) {
      int col = bn * 128 + wcol + n * 16 + (lane & 15);
      float cb = (kz == 0) ? conv_b[col] : 0.f;
#pragma unroll
      for (int j = 0; j < 4; ++j) {
        int row = bm * 128 + wrow + m * 16 + (lane >> 4) * 4 + j;
        dst[(size_t)row * NC + col] = acc[m][n][j] + cb;
      }
    }
}

// ---------------- 4) fused reduce: BN partial stats + pool sum/max/min per (bt,c) ----------------
__global__ __launch_bounds__(384)
void reduce_all(const float* __restrict__ p0, const float* __restrict__ p1,
                const float* __restrict__ p2, const float* __restrict__ p3,
                float* __restrict__ sarr, float* __restrict__ sqarr,
                float* __restrict__ mxarr, float* __restrict__ mnarr) {
  int bt = blockIdx.x, c = threadIdx.x;
  size_t base = (size_t)bt * HWO * NC + c;
  float s = 0.f, sq = 0.f, mx = -3.4e38f, mn = 3.4e38f;
#pragma unroll 6
  for (int hw = 0; hw < HWO; ++hw) {
    size_t off = base + (size_t)hw * NC;
    float v = p0[off] + p1[off] + p2[off] + p3[off];
    s += v; sq += v * v;
    mx = fmaxf(mx, v); mn = fminf(mn, v);
  }
  int o = bt * NC + c;
  sarr[o] = s; sqarr[o] = sq; mxarr[o] = mx; mnarr[o] = mn;
}

// ---------------- 4b) BN finalize: reduce 512 bt-partials per channel ----------------
__global__ __launch_bounds__(384)
void bn_fin(const float* __restrict__ sarr, const float* __restrict__ sqarr,
            const float* __restrict__ bn_g, const float* __restrict__ bn_b,
            float* __restrict__ bnsc, float* __restrict__ bnsh) {
  int c = threadIdx.x;
  float s = 0.f, sq = 0.f;
#pragma unroll 8
  for (int i = 0; i < 512; ++i) {
    s += sarr[i * NC + c];
    sq += sqarr[i * NC + c];
  }
  float mean = s / (float)MCONV;
  float var = sq / (float)MCONV - mean * mean;
  float sc = bn_g[c] / sqrtf(var + 1e-5f);
  bnsc[c] = sc;
  bnsh[c] = bn_b[c] - mean * sc;
}

// ---------------- 5) LayerNorm over pooled features (tiny reads) ----------------
__global__ __launch_bounds__(384)
void pool_ln(const float* __restrict__ sarr, const float* __restrict__ mxarr,
             const float* __restrict__ mnarr,
             const float* __restrict__ bnsc, const float* __restrict__ bnsh,
             const float* __restrict__ ln_g, const float* __restrict__ ln_b,
             float* __restrict__ y) {
  __shared__ float r1[6], r2[6], stats[2];
  int bt = blockIdx.x, c = threadIdx.x;
  int o = bt * NC + c;
  float sc = bnsc[c], sh = bnsh[c];
  float meanv = sarr[o] * (1.f / 36.f) * sc + sh;
  float mxv = (sc >= 0.f ? mxarr[o] : mnarr[o]) * sc + sh;
  float v1 = meanv + mxv;
  float v2 = meanv * meanv + mxv * mxv;
#pragma unroll
  for (int off = 32; off; off >>= 1) {
    v1 += __shfl_down(v1, off, 64);
    v2 += __shfl_down(v2, off, 64);
  }
  if ((c & 63) == 0) { r1[c >> 6] = v1; r2[c >> 6] = v2; }
  __syncthreads();
  if (c == 0) {
    float S1 = 0.f, S2 = 0.f;
#pragma unroll
    for (int i = 0; i < 6; ++i) { S1 += r1[i]; S2 += r2[i]; }
    float mu = S1 / (float)C2;
    float var = S2 / (float)C2 - mu * mu;
    stats[0] = mu;
    stats[1] = 1.0f / sqrtf(var + 1e-5f);
  }
  __syncthreads();
  float mu = stats[0], rstd = stats[1];
  y[(size_t)bt * C2 + c] = (meanv - mu) * rstd * ln_g[c] + ln_b[c];
  y[(size_t)bt * C2 + 384 + c] = (mxv - mu) * rstd * ln_g[384 + c] + ln_b[384 + c];
}

// ---------------- 6) small fp32 GEMM (+gelu, optional fused x2 build / gmean epilogue) ----------------
template <int GELU, int X2, int GM>
__global__ __launch_bounds__(256)
void gemm64(const float* __restrict__ A, const float* __restrict__ gmv,
            const float* __restrict__ Wm,
            const float* __restrict__ bias, float* __restrict__ Cm,
            int K, int N, float* __restrict__ gmout) {
  __shared__ float As[64][17];
  __shared__ float Bs[16][68];
  __shared__ float gmred[16][64];
  int tid = threadIdx.x;
  int tx = tid & 15, ty = tid >> 4;
  int m0 = blockIdx.y * 64, n0 = blockIdx.x * 64;
  int ar = tid >> 2, ak = (tid & 3) * 4;
  int br = tid >> 4, bc = (tid & 15) * 4;
  float acc[4][4] = {};
  for (int kt = 0; kt < K; kt += 16) {
    int kcol = kt + ak;
    float4 av;
    if (X2 && kcol >= 384)
      av = *(const float4*)(gmv + ((m0 + ar) >> 4) * 384 + (kcol - 384));
    else
      av = *(const float4*)(A + (size_t)(m0 + ar) * K + kcol);
    float4 bv = *(const float4*)(Wm + (size_t)(kt + br) * N + n0 + bc);
    As[ar][ak + 0] = av.x; As[ar][ak + 1] = av.y;
    As[ar][ak + 2] = av.z; As[ar][ak + 3] = av.w;
    Bs[br][bc + 0] = bv.x; Bs[br][bc + 1] = bv.y;
    Bs[br][bc + 2] = bv.z; Bs[br][bc + 3] = bv.w;
    __syncthreads();
#pragma unroll
    for (int kk = 0; kk < 16; ++kk) {
      float a0 = As[ty * 4 + 0][kk], a1 = As[ty * 4 + 1][kk];
      float a2 = As[ty * 4 + 2][kk], a3 = As[ty * 4 + 3][kk];
      float b0 = Bs[kk][tx * 4 + 0], b1 = Bs[kk][tx * 4 + 1];
      float b2 = Bs[kk][tx * 4 + 2], b3 = Bs[kk][tx * 4 + 3];
      acc[0][0] += a0 * b0; acc[0][1] += a0 * b1; acc[0][2] += a0 * b2; acc[0][3] += a0 * b3;
      acc[1][0] += a1 * b0; acc[1][1] += a1 * b1; acc[1][2] += a1 * b2; acc[1][3] += a1 * b3;
      acc[2][0] += a2 * b0; acc[2][1] += a2 * b1; acc[2][2] += a2 * b2; acc[2][3] += a2 * b3;
      acc[3][0] += a3 * b0; acc[3][1] += a3 * b1; acc[3][2] += a3 * b2; acc[3][3] += a3 * b3;
    }
    __syncthreads();
  }
  float vout[4][4];
#pragma unroll
  for (int i = 0; i < 4; ++i) {
    int row = m0 + ty * 4 + i;
#pragma unroll
    for (int j = 0; j < 4; ++j) {
      int col = n0 + tx * 4 + j;
      float v = acc[i][j] + bias[col];
      if (GELU) v = 0.5f * v * (1.0f + erff(v * 0.70710678118654752f));
      vout[i][j] = v;
      Cm[(size_t)row * N + col] = v;
    }
  }
  if (GM && n0 >= 384) {
#pragma unroll
    for (int j = 0; j < 4; ++j)
      gmred[ty][tx * 4 + j] = vout[0][j] + vout[1][j] + vout[2][j] + vout[3][j];
    __syncthreads();
    int b_l = tid >> 6, col = tid & 63;
    float g = (gmred[b_l * 4 + 0][col] + gmred[b_l * 4 + 1][col] +
               gmred[b_l * 4 + 2][col] + gmred[b_l * 4 + 3][col]) * (1.f / 16.f);
    gmout[(blockIdx.y * 4 + b_l) * 384 + (n0 - 384) + col] = g;
  }
}

// ---------------- 9) score head: 8 sample-chunks per b, per-chunk counts ----------------
__global__ __launch_bounds__(256)
void score_head(const float* __restrict__ h2, const float* __restrict__ w3,
                const float* __restrict__ b3, const float* __restrict__ noise,
                unsigned* __restrict__ pcnt, float* __restrict__ out_inds) {
  int b = blockIdx.x >> 3, chunk = blockIdx.x & 7;
  int tid = threadIdx.x;
  int lane = tid & 63, wv = tid >> 6;
  __shared__ float sv[16], sn[16];
  __shared__ unsigned cnt[256];
  for (int t = wv; t < 16; t += 4) {
    const float* hr = h2 + ((size_t)b * 16 + t) * 192;
    float p = 0.f;
    for (int i = lane; i < 192; i += 64) p += hr[i] * w3[i];
#pragma unroll
    for (int off = 32; off; off >>= 1) p += __shfl_down(p, off, 64);
    if (lane == 0) sv[t] = p + b3[0];
  }
  cnt[tid] = 0;
  __syncthreads();
  if (tid == 0) {
    float mn = sv[0], mx = sv[0];
    for (int t = 1; t < 16; ++t) { mn = fminf(mn, sv[t]); mx = fmaxf(mx, sv[t]); }
    float inv = 1.0f / (mx - mn + 1e-5f);
    for (int t = 0; t < 16; ++t) sn[t] = (sv[t] - mn) * inv;
  }
  __syncthreads();
  if (chunk == 0 && tid < 16) {
    int t = tid, r = 0;
    for (int u = 0; u < 16; ++u)
      r += (sv[u] < sv[t]) || (sv[u] == sv[t] && u < t);
    out_inds[b * 16 + r] = (float)t;
  }
  if (tid < 125) {
    int s = chunk * 125 + tid;
    const float* nz = noise + ((size_t)b * NSAMP + s) * 16;
    float pert[16];
#pragma unroll
    for (int t = 0; t < 16; ++t) pert[t] = sn[t] + 0.05f * nz[t];
    unsigned tm = 0, bm2 = 0;
#pragma unroll
    for (int t = 0; t < 16; ++t) {
      int ct = 0, cb = 0;
#pragma unroll
      for (int u = 0; u < 16; ++u) {
        ct += (pert[u] > pert[t]) || (pert[u] == pert[t] && u < t);
        cb += (pert[u] < pert[t]) || (pert[u] == pert[t] && u < t);
      }
      if (ct < 8) tm |= 1u << t;
      if (cb < 8) bm2 |= 1u << t;
    }
    int j = 0, jb = 0;
#pragma unroll
    for (int t = 0; t < 16; ++t) {
      if (tm & (1u << t)) { if (j < 8) atomicAdd(&cnt[j * 16 + t], 1u); ++j; }
      if (bm2 & (1u << t)) { if (jb < 8) atomicAdd(&cnt[128 + jb * 16 + t], 1u); ++jb; }
    }
  }
  __syncthreads();
  pcnt[(size_t)(b * 8 + chunk) * 256 + tid] = cnt[tid];
}

// ---------------- 10) weighted gather of frames (float4), sums 8 count-chunks ----------------
__global__ __launch_bounds__(256)
void gather_k(const float* __restrict__ frames, const unsigned* __restrict__ pcnt,
              float* __restrict__ out) {
  int bid = blockIdx.x;             // 4 (b,c) pairs per block; same b (384%4==0)
  int tid = threadIdx.x;
  int b = (bid * 4) / NC;
  __shared__ float wt[256];
  {
    unsigned s = 0;
    const unsigned* pc = pcnt + (size_t)b * 8 * 256 + tid;
#pragma unroll
    for (int ch = 0; ch < 8; ++ch) s += pc[ch * 256];
    wt[tid] = (float)s / 1000.0f;
  }
  __syncthreads();
  if (tid >= 196) return;
  int cc = tid / 49, q = tid - cc * 49;
  int bc = bid * 4 + cc;
  const float4* src = (const float4*)(frames + (size_t)bc * NT * HWI) + q;
  float4 v[16];
#pragma unroll
  for (int t = 0; t < 16; ++t) v[t] = src[t * 49];
  float4* o1 = (float4*)(out + (size_t)bc * TOPK * HWI) + q;
  float4* o2 = (float4*)(out + OUT_TOPK_ELEMS + (size_t)bc * TOPK * HWI) + q;
#pragma unroll
  for (int k = 0; k < TOPK; ++k) {
    float4 st = {0.f, 0.f, 0.f, 0.f}, sb = {0.f, 0.f, 0.f, 0.f};
#pragma unroll
    for (int t = 0; t < 16; ++t) {
      float a = wt[k * 16 + t], bw = wt[128 + k * 16 + t];
      st.x += a * v[t].x; st.y += a * v[t].y; st.z += a * v[t].z; st.w += a * v[t].w;
      sb.x += bw * v[t].x; sb.y += bw * v[t].y; sb.z += bw * v[t].z; sb.w += bw * v[t].w;
    }
    o1[k * 49] = st;
    o2[k * 49] = sb;
  }
}

// ---------------- launcher ----------------
extern "C" void kernel_launch(void* const* d_in, const int* in_sizes, int n_in,
                              void* d_out, int out_size, void* d_ws, size_t ws_size,
                              hipStream_t stream) {
  const float* frames = (const float*)d_in[0];
  const float* noise  = (const float*)d_in[1];
  const float* conv_w = (const float*)d_in[2];
  const float* conv_b = (const float*)d_in[3];
  const float* bn_g   = (const float*)d_in[4];
  const float* bn_b   = (const float*)d_in[5];
  const float* ln_g   = (const float*)d_in[6];
  const float* ln_b   = (const float*)d_in[7];
  const float* lin_w  = (const float*)d_in[8];
  const float* lin_b  = (const float*)d_in[9];
  const float* w1     = (const float*)d_in[10];
  const float* b1     = (const float*)d_in[11];
  const float* w2     = (const float*)d_in[12];
  const float* b2     = (const float*)d_in[13];
  const float* w3     = (const float*)d_in[14];
  const float* b3     = (const float*)d_in[15];

  char* ws = (char*)d_ws;
  unsigned short* fhi = (unsigned short*)(ws + OFF_FHI);
  unsigned short* flo = (unsigned short*)(ws + OFF_FLO);
  unsigned short* whi = (unsigned short*)(ws + OFF_WHI);
  unsigned short* wlo = (unsigned short*)(ws + OFF_WLO);
  float* p0    = (float*)(ws + OFF_CONV);
  float* sarr  = (float*)(ws + OFF_SARR);
  float* sqarr = (float*)(ws + OFF_SQAR);
  float* mxarr = (float*)(ws + OFF_MXAR);
  float* mnarr = (float*)(ws + OFF_MNAR);
  float* bnsc  = (float*)(ws + OFF_BNSC);
  float* bnsh  = (float*)(ws + OFF_BNSH);
  float* y     = (float*)(ws + OFF_Y);
  float* x1    = (float*)(ws + OFF_X1);
  float* gm    = (float*)(ws + OFF_GM);
  float* h1    = (float*)(ws + OFF_H1);
  float* h2    = (float*)(ws + OFF_H2);
  unsigned* pcnt = (unsigned*)(ws + OFF_PCNT);
  float* out   = (float*)d_out;
  // p1..p3 scratch live in d_out (extent 21.2M floats < inds offset 38.5M);
  // gather_k overwrites them later on the same serial stream.
  float* p1    = out;
  float* p2    = out + PELEMS;
  float* p3    = out + 2 * (size_t)PELEMS;

  split_all<<<3456, 256, 0, stream>>>(frames, conv_w, fhi, flo, whi, wlo);
  conv_gemm<<<1728, 256, 0, stream>>>(fhi, flo, whi, wlo, conv_b, p0, p1, p2, p3);
  reduce_all<<<512, 384, 0, stream>>>(p0, p1, p2, p3, sarr, sqarr, mxarr, mnarr);
  bn_fin<<<1, 384, 0, stream>>>(sarr, sqarr, bn_g, bn_b, bnsc, bnsh);
  pool_ln<<<512, 384, 0, stream>>>(sarr, mxarr, mnarr, bnsc, bnsh, ln_g, ln_b, y);
  gemm64<1, 0, 1><<<dim3(12, 8), 256, 0, stream>>>(y, nullptr, lin_w, lin_b, x1, 768, 768, gm);
  gemm64<1, 1, 0><<<dim3(6, 8), 256, 0, stream>>>(x1, gm, w1, b1, h1, 768, 384, nullptr);
  gemm64<1, 0, 0><<<dim3(3, 8), 256, 0, stream>>>(h1, nullptr, w2, b2, h2, 384, 192, nullptr);
  score_head<<<256, 256, 0, stream>>>(h2, w3, b3, noise, pcnt, out + OUT_INDS_OFF);
  gather_k<<<3072, 256, 0, stream>>>(frames, pcnt, out);
}

// Round 8
// 479.181 us; speedup vs baseline: 1.0684x; 1.0684x over previous
//
#include <hip/hip_runtime.h>
#include <hip/hip_bf16.h>
#include <cstdint>

// ---------------- problem constants ----------------
#define NB 32
#define NC 384
#define NT 16
#define NH 14
#define NW 14
#define HWI 196          // 14*14
#define HOW 6            // conv out H,W
#define HWO 36           // 6*6
#define C2 768
#define MCONV (NB*NT*HWO)   // 18432
#define KCONV 3456          // 384*9
#define TOPK 8
#define NSAMP 1000
#define OUT_TOPK_ELEMS (NB*NC*TOPK*HWI)  // 19267584
#define OUT_INDS_OFF   (2*OUT_TOPK_ELEMS) // 38535168
#define PELEMS (MCONV*NC)                 // 7077888 per partial

// ---------------- ws layout (bytes) ----------------
#define OFF_FHI  0ull
#define OFF_FLO  77070336ull
#define OFF_WHI  154140672ull
#define OFF_WLO  156794880ull
#define OFF_CONV 159449088ull
// region A overlays FHI after conv is done (written only post-conv):
#define OFF_SARR 0ull            // 512*384*4 = 786432
#define OFF_SQAR 786432ull
#define OFF_MXAR 1572864ull
#define OFF_MNAR 2359296ull
#define OFF_BNSC 3145728ull
#define OFF_BNSH 3147264ull
#define OFF_Y    3148800ull      // 512*768*4 = 1572864
#define OFF_X1   4721664ull
#define OFF_GM   6294528ull      // 49152
#define OFF_H1   6343680ull      // 786432
#define OFF_H2   7130112ull      // 393216
#define OFF_PCNT 7523328ull      // 32*8*256*4 = 262144
#define OFF_PARTA 7785472ull     // 32*768*4 = 98304

typedef __attribute__((ext_vector_type(4))) float f32x4;
typedef __attribute__((ext_vector_type(8))) short bf16x8;

__device__ __forceinline__ unsigned short f2bf(float f) {
  unsigned u = __float_as_uint(f);
  unsigned r = (u + 0x7FFFu + ((u >> 16) & 1u)) >> 16;  // RN-even
  return (unsigned short)r;
}
__device__ __forceinline__ float bf2f(unsigned short u) {
  return __uint_as_float(((unsigned)u) << 16);
}

__device__ __forceinline__ void gload_lds16(const void* gptr, void* lptr) {
  __builtin_amdgcn_global_load_lds(
      (const __attribute__((address_space(1))) unsigned int*)gptr,
      (__attribute__((address_space(3))) unsigned int*)lptr, 16, 0, 0);
}

// ---------------- 1) fused: frames -> (b,t,hw,c) bf16 hi/lo  AND  conv_w transpose ----------------
__global__ __launch_bounds__(256)
void split_all(const float* __restrict__ fr, const float* __restrict__ cw,
               unsigned short* __restrict__ fhi, unsigned short* __restrict__ flo,
               unsigned short* __restrict__ whi, unsigned short* __restrict__ wlo) {
  __shared__ char smem[64 * 197 * 4];
  int bid = blockIdx.x;
  if (bid < 3072) {
    unsigned int (*tile)[197] = (unsigned int (*)[197])smem;
    int cb = bid % 6, bt = bid / 6;
    int b = bt >> 4, t = bt & 15;
    const float* src = fr + (((size_t)b * NC + cb * 64) * NT + t) * HWI;
    for (int i = threadIdx.x; i < 64 * 49; i += 256) {
      int c = i / 49, q = i - c * 49;
      float4 v = *(const float4*)(src + (size_t)c * (NT * HWI) + q * 4);
      float vv[4] = {v.x, v.y, v.z, v.w};
#pragma unroll
      for (int u = 0; u < 4; ++u) {
        unsigned short h = f2bf(vv[u]);
        unsigned short l = f2bf(vv[u] - bf2f(h));
        tile[c][q * 4 + u] = ((unsigned)h << 16) | (unsigned)l;
      }
    }
    __syncthreads();
    size_t obase = ((size_t)bt * HWI) * NC + cb * 64;
    for (int i = threadIdx.x; i < 196 * 8; i += 256) {
      int hw = i >> 3, c8 = i & 7;
      bf16x8 vh, vl;
#pragma unroll
      for (int u = 0; u < 8; ++u) {
        unsigned p = tile[c8 * 8 + u][hw];
        vh[u] = (short)(p >> 16);
        vl[u] = (short)(p & 0xffff);
      }
      size_t o = obase + (size_t)hw * NC + c8 * 8;
      *(bf16x8*)(fhi + o) = vh;
      *(bf16x8*)(flo + o) = vl;
    }
  } else {
    float* t = (float*)smem;
    int co = bid - 3072;
    const float* src = cw + (size_t)co * KCONV;
    for (int i = threadIdx.x; i < KCONV / 4; i += 256)
      *(float4*)&t[i * 4] = *(const float4*)&src[i * 4];
    __syncthreads();
    unsigned short* oh = whi + (size_t)co * KCONV;
    unsigned short* ol = wlo + (size_t)co * KCONV;
    for (int i = threadIdx.x; i < KCONV; i += 256) {
      int c9 = i / NC, ci = i - c9 * NC;
      float v = t[ci * 9 + c9];
      unsigned short h = f2bf(v);
      oh[i] = h; ol[i] = f2bf(v - bf2f(h));
    }
  }
}

// ---------------- 3) conv implicit GEMM, split-bf16 3-product, split-K=4, swizzled LDS ----------------
// LDS swizzle verified conflict-free (R4: SQ_LDS_BANK_CONFLICT=0).
// Linear block decode (R5-proven 174us; R7's XCD decode regressed to 187 — reverted).
__global__ __launch_bounds__(256, 4)
void conv_gemm(const unsigned short* __restrict__ fhi,
               const unsigned short* __restrict__ flo,
               const unsigned short* __restrict__ whi,
               const unsigned short* __restrict__ wlo,
               const float* __restrict__ conv_b,
               float* __restrict__ p0, float* __restrict__ p1,
               float* __restrict__ p2, float* __restrict__ p3) {
  __shared__ unsigned short sAhi[128 * 32], sAlo[128 * 32];
  __shared__ unsigned short sBhi[128 * 32], sBlo[128 * 32];
  const int tid = threadIdx.x;
  const int lane = tid & 63;
  const int wv = tid >> 6;
  const int bid = blockIdx.x;
  const int bm = bid % 144;
  const int r  = bid / 144;        // 0..11
  const int bn = r % 3;
  const int kz = r / 3;            // 0..3

  int aoff[2], boff[2];
#pragma unroll
  for (int j = 0; j < 2; ++j) {
    int l = (wv * 2 + j) * 64 + lane;
    int row = l >> 2;
    int chunk = (l & 3) ^ ((l >> 3) & 3);   // swizzled source chunk
    int m = bm * 128 + row;
    int wo = m % 6; int tmp = m / 6;
    int ho = tmp % 6; tmp /= 6;     // tmp = b*16+t
    aoff[j] = ((tmp * HWI) + (2 * ho) * NW + 2 * wo) * NC + chunk * 8;
    int co = bn * 128 + row;
    boff[j] = co * KCONV + chunk * 8;
  }

  f32x4 acc[4][4];
#pragma unroll
  for (int i = 0; i < 4; ++i)
#pragma unroll
    for (int j = 0; j < 4; ++j) acc[i][j] = (f32x4){0.f, 0.f, 0.f, 0.f};

  const int wrow = (wv >> 1) * 64;
  const int wcol = (wv & 1) * 64;
  const int fr_row = lane & 15;
  const int slot8 = (((lane >> 4) ^ ((fr_row >> 1) & 3))) * 8;

  int c9  = (kz * 27) / 12;
  int rem = (kz * 27) % 12;
  for (int s = 0; s < 27; ++s) {
    int kh = c9 / 3, kw = c9 - kh * 3;
    int soffA = (kh * NW + kw) * NC + rem * 32;
    int soffB = c9 * NC + rem * 32;
#pragma unroll
    for (int j = 0; j < 2; ++j) {
      char* ldsA  = (char*)sAhi + (wv * 2 + j) * 1024;
      char* ldsAl = (char*)sAlo + (wv * 2 + j) * 1024;
      char* ldsB  = (char*)sBhi + (wv * 2 + j) * 1024;
      char* ldsBl = (char*)sBlo + (wv * 2 + j) * 1024;
      gload_lds16(fhi + aoff[j] + soffA, ldsA);
      gload_lds16(flo + aoff[j] + soffA, ldsAl);
      gload_lds16(whi + boff[j] + soffB, ldsB);
      gload_lds16(wlo + boff[j] + soffB, ldsBl);
    }
    __syncthreads();
    bf16x8 ah[4], al[4], bh[4], bl[4];
#pragma unroll
    for (int m = 0; m < 4; ++m) {
      int rr = wrow + m * 16 + fr_row;
      ah[m] = *(const bf16x8*)&sAhi[rr * 32 + slot8];
      al[m] = *(const bf16x8*)&sAlo[rr * 32 + slot8];
    }
#pragma unroll
    for (int n = 0; n < 4; ++n) {
      int rr = wcol + n * 16 + fr_row;
      bh[n] = *(const bf16x8*)&sBhi[rr * 32 + slot8];
      bl[n] = *(const bf16x8*)&sBlo[rr * 32 + slot8];
    }
#pragma unroll
    for (int m = 0; m < 4; ++m)
#pragma unroll
      for (int n = 0; n < 4; ++n) {
        acc[m][n] = __builtin_amdgcn_mfma_f32_16x16x32_bf16(ah[m], bh[n], acc[m][n], 0, 0, 0);
        acc[m][n] = __builtin_amdgcn_mfma_f32_16x16x32_bf16(ah[m], bl[n], acc[m][n], 0, 0, 0);
        acc[m][n] = __builtin_amdgcn_mfma_f32_16x16x32_bf16(al[m], bh[n], acc[m][n], 0, 0, 0);
      }
    __syncthreads();
    if (++rem == 12) { rem = 0; ++c9; }
  }

  float* dst = (kz == 0) ? p0 : (kz == 1) ? p1 : (kz == 2) ? p2 : p3;
#pragma unroll
  for (int m = 0; m < 4; ++m)
#pragma unroll
    for (int n = 0; n < 4; ++n) {
      int col = bn * 128 + wcol + n * 16 + (lane & 15);
      float cb = (kz == 0) ? conv_b[col] : 0.f;
#pragma unroll
      for (int j = 0; j < 4; ++j) {
        int row = bm * 128 + wrow + m * 16 + (lane >> 4) * 4 + j;
        dst[(size_t)row * NC + col] = acc[m][n][j] + cb;
      }
    }
}

// ---------------- 4) fused reduce: BN partial stats + pool sum/max/min per (bt,c) ----------------
__global__ __launch_bounds__(384)
void reduce_all(const float* __restrict__ p0, const float* __restrict__ p1,
                const float* __restrict__ p2, const float* __restrict__ p3,
                float* __restrict__ sarr, float* __restrict__ sqarr,
                float* __restrict__ mxarr, float* __restrict__ mnarr) {
  int bt = blockIdx.x, c = threadIdx.x;
  size_t base = (size_t)bt * HWO * NC + c;
  float s = 0.f, sq = 0.f, mx = -3.4e38f, mn = 3.4e38f;
#pragma unroll 6
  for (int hw = 0; hw < HWO; ++hw) {
    size_t off = base + (size_t)hw * NC;
    float v = p0[off] + p1[off] + p2[off] + p3[off];
    s += v; sq += v * v;
    mx = fmaxf(mx, v); mn = fminf(mn, v);
  }
  int o = bt * NC + c;
  sarr[o] = s; sqarr[o] = sq; mxarr[o] = mx; mnarr[o] = mn;
}

// ---------------- 4b) BN finalize, two-stage ----------------
__global__ __launch_bounds__(384)
void bn_finA(const float* __restrict__ sarr, const float* __restrict__ sqarr,
             float* __restrict__ partA) {
  int c = threadIdx.x;
  int b0 = blockIdx.x * 16;
  float s = 0.f, sq = 0.f;
#pragma unroll
  for (int i = 0; i < 16; ++i) {
    s += sarr[(b0 + i) * NC + c];
    sq += sqarr[(b0 + i) * NC + c];
  }
  partA[blockIdx.x * 768 + c] = s;
  partA[blockIdx.x * 768 + 384 + c] = sq;
}

__global__ __launch_bounds__(384)
void bn_finB(const float* __restrict__ partA, const float* __restrict__ bn_g,
             const float* __restrict__ bn_b, float* __restrict__ bnsc,
             float* __restrict__ bnsh) {
  int c = threadIdx.x;
  float s = 0.f, sq = 0.f;
#pragma unroll
  for (int i = 0; i < 32; ++i) {
    s += partA[i * 768 + c];
    sq += partA[i * 768 + 384 + c];
  }
  float mean = s / (float)MCONV;
  float var = sq / (float)MCONV - mean * mean;
  float sc = bn_g[c] / sqrtf(var + 1e-5f);
  bnsc[c] = sc;
  bnsh[c] = bn_b[c] - mean * sc;
}

// ---------------- 5) LayerNorm over pooled features (tiny reads) ----------------
__global__ __launch_bounds__(384)
void pool_ln(const float* __restrict__ sarr, const float* __restrict__ mxarr,
             const float* __restrict__ mnarr,
             const float* __restrict__ bnsc, const float* __restrict__ bnsh,
             const float* __restrict__ ln_g, const float* __restrict__ ln_b,
             float* __restrict__ y) {
  __shared__ float r1[6], r2[6], stats[2];
  int bt = blockIdx.x, c = threadIdx.x;
  int o = bt * NC + c;
  float sc = bnsc[c], sh = bnsh[c];
  float meanv = sarr[o] * (1.f / 36.f) * sc + sh;
  float mxv = (sc >= 0.f ? mxarr[o] : mnarr[o]) * sc + sh;
  float v1 = meanv + mxv;
  float v2 = meanv * meanv + mxv * mxv;
#pragma unroll
  for (int off = 32; off; off >>= 1) {
    v1 += __shfl_down(v1, off, 64);
    v2 += __shfl_down(v2, off, 64);
  }
  if ((c & 63) == 0) { r1[c >> 6] = v1; r2[c >> 6] = v2; }
  __syncthreads();
  if (c == 0) {
    float S1 = 0.f, S2 = 0.f;
#pragma unroll
    for (int i = 0; i < 6; ++i) { S1 += r1[i]; S2 += r2[i]; }
    float mu = S1 / (float)C2;
    float var = S2 / (float)C2 - mu * mu;
    stats[0] = mu;
    stats[1] = 1.0f / sqrtf(var + 1e-5f);
  }
  __syncthreads();
  float mu = stats[0], rstd = stats[1];
  y[(size_t)bt * C2 + c] = (meanv - mu) * rstd * ln_g[c] + ln_b[c];
  y[(size_t)bt * C2 + 384 + c] = (mxv - mu) * rstd * ln_g[384 + c] + ln_b[384 + c];
}

// ---------------- 6) small fp32 GEMM (+gelu, optional fused x2 build / gmean epilogue) ----------------
template <int GELU, int X2, int GM>
__global__ __launch_bounds__(256)
void gemm64(const float* __restrict__ A, const float* __restrict__ gmv,
            const float* __restrict__ Wm,
            const float* __restrict__ bias, float* __restrict__ Cm,
            int K, int N, float* __restrict__ gmout) {
  __shared__ float As[64][17];
  __shared__ float Bs[16][68];
  __shared__ float gmred[16][64];
  int tid = threadIdx.x;
  int tx = tid & 15, ty = tid >> 4;
  int m0 = blockIdx.y * 64, n0 = blockIdx.x * 64;
  int ar = tid >> 2, ak = (tid & 3) * 4;
  int br = tid >> 4, bc = (tid & 15) * 4;
  float acc[4][4] = {};
  for (int kt = 0; kt < K; kt += 16) {
    int kcol = kt + ak;
    float4 av;
    if (X2 && kcol >= 384)
      av = *(const float4*)(gmv + ((m0 + ar) >> 4) * 384 + (kcol - 384));
    else
      av = *(const float4*)(A + (size_t)(m0 + ar) * K + kcol);
    float4 bv = *(const float4*)(Wm + (size_t)(kt + br) * N + n0 + bc);
    As[ar][ak + 0] = av.x; As[ar][ak + 1] = av.y;
    As[ar][ak + 2] = av.z; As[ar][ak + 3] = av.w;
    Bs[br][bc + 0] = bv.x; Bs[br][bc + 1] = bv.y;
    Bs[br][bc + 2] = bv.z; Bs[br][bc + 3] = bv.w;
    __syncthreads();
#pragma unroll
    for (int kk = 0; kk < 16; ++kk) {
      float a0 = As[ty * 4 + 0][kk], a1 = As[ty * 4 + 1][kk];
      float a2 = As[ty * 4 + 2][kk], a3 = As[ty * 4 + 3][kk];
      float b0 = Bs[kk][tx * 4 + 0], b1 = Bs[kk][tx * 4 + 1];
      float b2 = Bs[kk][tx * 4 + 2], b3 = Bs[kk][tx * 4 + 3];
      acc[0][0] += a0 * b0; acc[0][1] += a0 * b1; acc[0][2] += a0 * b2; acc[0][3] += a0 * b3;
      acc[1][0] += a1 * b0; acc[1][1] += a1 * b1; acc[1][2] += a1 * b2; acc[1][3] += a1 * b3;
      acc[2][0] += a2 * b0; acc[2][1] += a2 * b1; acc[2][2] += a2 * b2; acc[2][3] += a2 * b3;
      acc[3][0] += a3 * b0; acc[3][1] += a3 * b1; acc[3][2] += a3 * b2; acc[3][3] += a3 * b3;
    }
    __syncthreads();
  }
  float vout[4][4];
#pragma unroll
  for (int i = 0; i < 4; ++i) {
    int row = m0 + ty * 4 + i;
#pragma unroll
    for (int j = 0; j < 4; ++j) {
      int col = n0 + tx * 4 + j;
      float v = acc[i][j] + bias[col];
      if (GELU) v = 0.5f * v * (1.0f + erff(v * 0.70710678118654752f));
      vout[i][j] = v;
      Cm[(size_t)row * N + col] = v;
    }
  }
  if (GM && n0 >= 384) {
#pragma unroll
    for (int j = 0; j < 4; ++j)
      gmred[ty][tx * 4 + j] = vout[0][j] + vout[1][j] + vout[2][j] + vout[3][j];
    __syncthreads();
    int b_l = tid >> 6, col = tid & 63;
    float g = (gmred[b_l * 4 + 0][col] + gmred[b_l * 4 + 1][col] +
               gmred[b_l * 4 + 2][col] + gmred[b_l * 4 + 3][col]) * (1.f / 16.f);
    gmout[(blockIdx.y * 4 + b_l) * 384 + (n0 - 384) + col] = g;
  }
}

// ---------------- 9) score head: 8 sample-chunks per b, per-chunk counts ----------------
__global__ __launch_bounds__(256)
void score_head(const float* __restrict__ h2, const float* __restrict__ w3,
                const float* __restrict__ b3, const float* __restrict__ noise,
                unsigned* __restrict__ pcnt, float* __restrict__ out_inds) {
  int b = blockIdx.x >> 3, chunk = blockIdx.x & 7;
  int tid = threadIdx.x;
  int lane = tid & 63, wv = tid >> 6;
  __shared__ float sv[16], sn[16];
  __shared__ unsigned cnt[256];
  for (int t = wv; t < 16; t += 4) {
    const float* hr = h2 + ((size_t)b * 16 + t) * 192;
    float p = 0.f;
    for (int i = lane; i < 192; i += 64) p += hr[i] * w3[i];
#pragma unroll
    for (int off = 32; off; off >>= 1) p += __shfl_down(p, off, 64);
    if (lane == 0) sv[t] = p + b3[0];
  }
  cnt[tid] = 0;
  __syncthreads();
  if (tid == 0) {
    float mn = sv[0], mx = sv[0];
    for (int t = 1; t < 16; ++t) { mn = fminf(mn, sv[t]); mx = fmaxf(mx, sv[t]); }
    float inv = 1.0f / (mx - mn + 1e-5f);
    for (int t = 0; t < 16; ++t) sn[t] = (sv[t] - mn) * inv;
  }
  __syncthreads();
  if (chunk == 0 && tid < 16) {
    int t = tid, r = 0;
    for (int u = 0; u < 16; ++u)
      r += (sv[u] < sv[t]) || (sv[u] == sv[t] && u < t);
    out_inds[b * 16 + r] = (float)t;
  }
  if (tid < 125) {
    int s = chunk * 125 + tid;
    const float* nz = noise + ((size_t)b * NSAMP + s) * 16;
    float pert[16];
#pragma unroll
    for (int t = 0; t < 16; ++t) pert[t] = sn[t] + 0.05f * nz[t];
    unsigned tm = 0, bm2 = 0;
#pragma unroll
    for (int t = 0; t < 16; ++t) {
      int ct = 0, cb = 0;
#pragma unroll
      for (int u = 0; u < 16; ++u) {
        ct += (pert[u] > pert[t]) || (pert[u] == pert[t] && u < t);
        cb += (pert[u] < pert[t]) || (pert[u] == pert[t] && u < t);
      }
      if (ct < 8) tm |= 1u << t;
      if (cb < 8) bm2 |= 1u << t;
    }
    int j = 0, jb = 0;
#pragma unroll
    for (int t = 0; t < 16; ++t) {
      if (tm & (1u << t)) { if (j < 8) atomicAdd(&cnt[j * 16 + t], 1u); ++j; }
      if (bm2 & (1u << t)) { if (jb < 8) atomicAdd(&cnt[128 + jb * 16 + t], 1u); ++jb; }
    }
  }
  __syncthreads();
  pcnt[(size_t)(b * 8 + chunk) * 256 + tid] = cnt[tid];
}

// ---------------- 10) weighted gather of frames (float4), sums 8 count-chunks ----------------
__global__ __launch_bounds__(256)
void gather_k(const float* __restrict__ frames, const unsigned* __restrict__ pcnt,
              float* __restrict__ out) {
  int bid = blockIdx.x;             // 4 (b,c) pairs per block; same b (384%4==0)
  int tid = threadIdx.x;
  int b = (bid * 4) / NC;
  __shared__ float wt[256];
  {
    unsigned s = 0;
    const unsigned* pc = pcnt + (size_t)b * 8 * 256 + tid;
#pragma unroll
    for (int ch = 0; ch < 8; ++ch) s += pc[ch * 256];
    wt[tid] = (float)s / 1000.0f;
  }
  __syncthreads();
  if (tid >= 196) return;
  int cc = tid / 49, q = tid - cc * 49;
  int bc = bid * 4 + cc;
  const float4* src = (const float4*)(frames + (size_t)bc * NT * HWI) + q;
  float4 v[16];
#pragma unroll
  for (int t = 0; t < 16; ++t) v[t] = src[t * 49];
  float4* o1 = (float4*)(out + (size_t)bc * TOPK * HWI) + q;
  float4* o2 = (float4*)(out + OUT_TOPK_ELEMS + (size_t)bc * TOPK * HWI) + q;
#pragma unroll
  for (int k = 0; k < TOPK; ++k) {
    float4 st = {0.f, 0.f, 0.f, 0.f}, sb = {0.f, 0.f, 0.f, 0.f};
#pragma unroll
    for (int t = 0; t < 16; ++t) {
      float a = wt[k * 16 + t], bw = wt[128 + k * 16 + t];
      st.x += a * v[t].x; st.y += a * v[t].y; st.z += a * v[t].z; st.w += a * v[t].w;
      sb.x += bw * v[t].x; sb.y += bw * v[t].y; sb.z += bw * v[t].z; sb.w += bw * v[t].w;
    }
    o1[k * 49] = st;
    o2[k * 49] = sb;
  }
}

// ---------------- launcher ----------------
extern "C" void kernel_launch(void* const* d_in, const int* in_sizes, int n_in,
                              void* d_out, int out_size, void* d_ws, size_t ws_size,
                              hipStream_t stream) {
  const float* frames = (const float*)d_in[0];
  const float* noise  = (const float*)d_in[1];
  const float* conv_w = (const float*)d_in[2];
  const float* conv_b = (const float*)d_in[3];
  const float* bn_g   = (const float*)d_in[4];
  const float* bn_b   = (const float*)d_in[5];
  const float* ln_g   = (const float*)d_in[6];
  const float* ln_b   = (const float*)d_in[7];
  const float* lin_w  = (const float*)d_in[8];
  const float* lin_b  = (const float*)d_in[9];
  const float* w1     = (const float*)d_in[10];
  const float* b1     = (const float*)d_in[11];
  const float* w2     = (const float*)d_in[12];
  const float* b2     = (const float*)d_in[13];
  const float* w3     = (const float*)d_in[14];
  const float* b3     = (const float*)d_in[15];

  char* ws = (char*)d_ws;
  unsigned short* fhi = (unsigned short*)(ws + OFF_FHI);
  unsigned short* flo = (unsigned short*)(ws + OFF_FLO);
  unsigned short* whi = (unsigned short*)(ws + OFF_WHI);
  unsigned short* wlo = (unsigned short*)(ws + OFF_WLO);
  float* p0    = (float*)(ws + OFF_CONV);
  float* sarr  = (float*)(ws + OFF_SARR);
  float* sqarr = (float*)(ws + OFF_SQAR);
  float* mxarr = (float*)(ws + OFF_MXAR);
  float* mnarr = (float*)(ws + OFF_MNAR);
  float* bnsc  = (float*)(ws + OFF_BNSC);
  float* bnsh  = (float*)(ws + OFF_BNSH);
  float* y     = (float*)(ws + OFF_Y);
  float* x1    = (float*)(ws + OFF_X1);
  float* gm    = (float*)(ws + OFF_GM);
  float* h1    = (float*)(ws + OFF_H1);
  float* h2    = (float*)(ws + OFF_H2);
  unsigned* pcnt = (unsigned*)(ws + OFF_PCNT);
  float* partA = (float*)(ws + OFF_PARTA);
  float* out   = (float*)d_out;
  // p1..p3 scratch live in d_out (extent 21.2M floats < inds offset 38.5M);
  // gather_k overwrites them later on the same serial stream.
  float* p1    = out;
  float* p2    = out + PELEMS;
  float* p3    = out + 2 * (size_t)PELEMS;

  split_all<<<3456, 256, 0, stream>>>(frames, conv_w, fhi, flo, whi, wlo);
  conv_gemm<<<1728, 256, 0, stream>>>(fhi, flo, whi, wlo, conv_b, p0, p1, p2, p3);
  reduce_all<<<512, 384, 0, stream>>>(p0, p1, p2, p3, sarr, sqarr, mxarr, mnarr);
  bn_finA<<<32, 384, 0, stream>>>(sarr, sqarr, partA);
  bn_finB<<<1, 384, 0, stream>>>(partA, bn_g, bn_b, bnsc, bnsh);
  pool_ln<<<512, 384, 0, stream>>>(sarr, mxarr, mnarr, bnsc, bnsh, ln_g, ln_b, y);
  gemm64<1, 0, 1><<<dim3(12, 8), 256, 0, stream>>>(y, nullptr, lin_w, lin_b, x1, 768, 768, gm);
  gemm64<1, 1, 0><<<dim3(6, 8), 256, 0, stream>>>(x1, gm, w1, b1, h1, 768, 384, nullptr);
  gemm64<1, 0, 0><<<dim3(3, 8), 256, 0, stream>>>(h1, nullptr, w2, b2, h2, 384, 192, nullptr);
  score_head<<<256, 256, 0, stream>>>(h2, w3, b3, noise, pcnt, out + OUT_INDS_OFF);
  gather_k<<<3072, 256, 0, stream>>>(frames, pcnt, out);
}

// Round 9
// 473.779 us; speedup vs baseline: 1.0806x; 1.0114x over previous
//
#include <hip/hip_runtime.h>
#include <hip/hip_bf16.h>
#include <cstdint>

// ---------------- problem constants ----------------
#define NB 32
#define NC 384
#define NT 16
#define NH 14
#define NW 14
#define HWI 196          // 14*14
#define HOW 6            // conv out H,W
#define HWO 36           // 6*6
#define C2 768
#define MCONV (NB*NT*HWO)   // 18432
#define KCONV 3456          // 384*9
#define TOPK 8
#define NSAMP 1000
#define OUT_TOPK_ELEMS (NB*NC*TOPK*HWI)  // 19267584
#define OUT_INDS_OFF   (2*OUT_TOPK_ELEMS) // 38535168
#define PELEMS (MCONV*NC)                 // 7077888 per partial

// ---------------- ws layout (bytes) ----------------
#define OFF_FHI  0ull
#define OFF_FLO  77070336ull
#define OFF_WHI  154140672ull
#define OFF_WLO  156794880ull
#define OFF_CONV 159449088ull
// region A overlays FHI after conv is done (written only post-conv):
#define OFF_SARR 0ull            // 512*384*4 = 786432
#define OFF_SQAR 786432ull
#define OFF_MXAR 1572864ull
#define OFF_MNAR 2359296ull
#define OFF_BNSC 3145728ull
#define OFF_BNSH 3147264ull
#define OFF_Y    3148800ull      // 512*768*4 = 1572864
#define OFF_X1   4721664ull
#define OFF_GM   6294528ull      // 49152
#define OFF_H1   6343680ull      // 786432
#define OFF_H2   7130112ull      // 393216
#define OFF_PCNT 7523328ull      // 32*8*256*4 = 262144
#define OFF_PARTA 7785472ull     // 32*768*4 = 98304

typedef __attribute__((ext_vector_type(4))) float f32x4;
typedef __attribute__((ext_vector_type(8))) short bf16x8;

__device__ __forceinline__ unsigned short f2bf(float f) {
  unsigned u = __float_as_uint(f);
  unsigned r = (u + 0x7FFFu + ((u >> 16) & 1u)) >> 16;  // RN-even
  return (unsigned short)r;
}
__device__ __forceinline__ float bf2f(unsigned short u) {
  return __uint_as_float(((unsigned)u) << 16);
}

__device__ __forceinline__ void gload_lds16(const void* gptr, void* lptr) {
  __builtin_amdgcn_global_load_lds(
      (const __attribute__((address_space(1))) unsigned int*)gptr,
      (__attribute__((address_space(3))) unsigned int*)lptr, 16, 0, 0);
}

// ---------------- 1) fused: frames -> (b,t,hw,c) bf16 hi/lo  AND  conv_w transpose ----------------
__global__ __launch_bounds__(256)
void split_all(const float* __restrict__ fr, const float* __restrict__ cw,
               unsigned short* __restrict__ fhi, unsigned short* __restrict__ flo,
               unsigned short* __restrict__ whi, unsigned short* __restrict__ wlo) {
  __shared__ char smem[64 * 197 * 4];
  int bid = blockIdx.x;
  if (bid < 3072) {
    unsigned int (*tile)[197] = (unsigned int (*)[197])smem;
    int cb = bid % 6, bt = bid / 6;
    int b = bt >> 4, t = bt & 15;
    const float* src = fr + (((size_t)b * NC + cb * 64) * NT + t) * HWI;
    for (int i = threadIdx.x; i < 64 * 49; i += 256) {
      int c = i / 49, q = i - c * 49;
      float4 v = *(const float4*)(src + (size_t)c * (NT * HWI) + q * 4);
      float vv[4] = {v.x, v.y, v.z, v.w};
#pragma unroll
      for (int u = 0; u < 4; ++u) {
        unsigned short h = f2bf(vv[u]);
        unsigned short l = f2bf(vv[u] - bf2f(h));
        tile[c][q * 4 + u] = ((unsigned)h << 16) | (unsigned)l;
      }
    }
    __syncthreads();
    size_t obase = ((size_t)bt * HWI) * NC + cb * 64;
    for (int i = threadIdx.x; i < 196 * 8; i += 256) {
      int hw = i >> 3, c8 = i & 7;
      bf16x8 vh, vl;
#pragma unroll
      for (int u = 0; u < 8; ++u) {
        unsigned p = tile[c8 * 8 + u][hw];
        vh[u] = (short)(p >> 16);
        vl[u] = (short)(p & 0xffff);
      }
      size_t o = obase + (size_t)hw * NC + c8 * 8;
      *(bf16x8*)(fhi + o) = vh;
      *(bf16x8*)(flo + o) = vl;
    }
  } else {
    float* t = (float*)smem;
    int co = bid - 3072;
    const float* src = cw + (size_t)co * KCONV;
    for (int i = threadIdx.x; i < KCONV / 4; i += 256)
      *(float4*)&t[i * 4] = *(const float4*)&src[i * 4];
    __syncthreads();
    unsigned short* oh = whi + (size_t)co * KCONV;
    unsigned short* ol = wlo + (size_t)co * KCONV;
    for (int i = threadIdx.x; i < KCONV; i += 256) {
      int c9 = i / NC, ci = i - c9 * NC;
      float v = t[ci * 9 + c9];
      unsigned short h = f2bf(v);
      oh[i] = h; ol[i] = f2bf(v - bf2f(h));
    }
  }
}

// ---------------- 3) conv implicit GEMM, split-bf16 3-product, split-K=2, swizzled LDS ----------------
// LDS swizzle verified conflict-free (R4: SQ_LDS_BANK_CONFLICT=0).
// Linear block decode (R5/R7 A/B: linear 174 vs XCD 187 — keep linear).
// Split-K=2 (R4-measured 181.6us conv): trades +7us conv for -113MB partial traffic vs K=4.
__global__ __launch_bounds__(256, 4)
void conv_gemm(const unsigned short* __restrict__ fhi,
               const unsigned short* __restrict__ flo,
               const unsigned short* __restrict__ whi,
               const unsigned short* __restrict__ wlo,
               const float* __restrict__ conv_b,
               float* __restrict__ p0, float* __restrict__ p1) {
  __shared__ unsigned short sAhi[128 * 32], sAlo[128 * 32];
  __shared__ unsigned short sBhi[128 * 32], sBlo[128 * 32];
  const int tid = threadIdx.x;
  const int lane = tid & 63;
  const int wv = tid >> 6;
  const int bid = blockIdx.x;
  // A-sharers (same bm) sit at bid+144*k -> 144%8==0 -> same XCD L2.
  const int bm = bid % 144;
  const int r  = bid / 144;        // 0..5
  const int bn = r % 3;
  const int kz = r / 3;            // 0..1

  int aoff[2], boff[2];
#pragma unroll
  for (int j = 0; j < 2; ++j) {
    int l = (wv * 2 + j) * 64 + lane;
    int row = l >> 2;
    int chunk = (l & 3) ^ ((l >> 3) & 3);   // swizzled source chunk
    int m = bm * 128 + row;
    int wo = m % 6; int tmp = m / 6;
    int ho = tmp % 6; tmp /= 6;     // tmp = b*16+t
    aoff[j] = ((tmp * HWI) + (2 * ho) * NW + 2 * wo) * NC + chunk * 8;
    int co = bn * 128 + row;
    boff[j] = co * KCONV + chunk * 8;
  }

  f32x4 acc[4][4];
#pragma unroll
  for (int i = 0; i < 4; ++i)
#pragma unroll
    for (int j = 0; j < 4; ++j) acc[i][j] = (f32x4){0.f, 0.f, 0.f, 0.f};

  const int wrow = (wv >> 1) * 64;
  const int wcol = (wv & 1) * 64;
  const int fr_row = lane & 15;
  const int slot8 = (((lane >> 4) ^ ((fr_row >> 1) & 3))) * 8;

  int c9  = kz ? 4 : 0;
  int rem = kz ? 6 : 0;
  for (int s = 0; s < 54; ++s) {
    int kh = c9 / 3, kw = c9 - kh * 3;
    int soffA = (kh * NW + kw) * NC + rem * 32;
    int soffB = c9 * NC + rem * 32;
#pragma unroll
    for (int j = 0; j < 2; ++j) {
      char* ldsA  = (char*)sAhi + (wv * 2 + j) * 1024;
      char* ldsAl = (char*)sAlo + (wv * 2 + j) * 1024;
      char* ldsB  = (char*)sBhi + (wv * 2 + j) * 1024;
      char* ldsBl = (char*)sBlo + (wv * 2 + j) * 1024;
      gload_lds16(fhi + aoff[j] + soffA, ldsA);
      gload_lds16(flo + aoff[j] + soffA, ldsAl);
      gload_lds16(whi + boff[j] + soffB, ldsB);
      gload_lds16(wlo + boff[j] + soffB, ldsBl);
    }
    __syncthreads();
    bf16x8 ah[4], al[4], bh[4], bl[4];
#pragma unroll
    for (int m = 0; m < 4; ++m) {
      int rr = wrow + m * 16 + fr_row;
      ah[m] = *(const bf16x8*)&sAhi[rr * 32 + slot8];
      al[m] = *(const bf16x8*)&sAlo[rr * 32 + slot8];
    }
#pragma unroll
    for (int n = 0; n < 4; ++n) {
      int rr = wcol + n * 16 + fr_row;
      bh[n] = *(const bf16x8*)&sBhi[rr * 32 + slot8];
      bl[n] = *(const bf16x8*)&sBlo[rr * 32 + slot8];
    }
#pragma unroll
    for (int m = 0; m < 4; ++m)
#pragma unroll
      for (int n = 0; n < 4; ++n) {
        acc[m][n] = __builtin_amdgcn_mfma_f32_16x16x32_bf16(ah[m], bh[n], acc[m][n], 0, 0, 0);
        acc[m][n] = __builtin_amdgcn_mfma_f32_16x16x32_bf16(ah[m], bl[n], acc[m][n], 0, 0, 0);
        acc[m][n] = __builtin_amdgcn_mfma_f32_16x16x32_bf16(al[m], bh[n], acc[m][n], 0, 0, 0);
      }
    __syncthreads();
    if (++rem == 12) { rem = 0; ++c9; }
  }

  float* dst = kz ? p1 : p0;
#pragma unroll
  for (int m = 0; m < 4; ++m)
#pragma unroll
    for (int n = 0; n < 4; ++n) {
      int col = bn * 128 + wcol + n * 16 + (lane & 15);
      float cb = kz ? 0.f : conv_b[col];
#pragma unroll
      for (int j = 0; j < 4; ++j) {
        int row = bm * 128 + wrow + m * 16 + (lane >> 4) * 4 + j;
        dst[(size_t)row * NC + col] = acc[m][n][j] + cb;
      }
    }
}

// ---------------- 4) fused reduce: BN partial stats + pool sum/max/min per (bt,c) ----------------
__global__ __launch_bounds__(384)
void reduce_all(const float* __restrict__ p0, const float* __restrict__ p1,
                float* __restrict__ sarr, float* __restrict__ sqarr,
                float* __restrict__ mxarr, float* __restrict__ mnarr) {
  int bt = blockIdx.x, c = threadIdx.x;
  size_t base = (size_t)bt * HWO * NC + c;
  float s = 0.f, sq = 0.f, mx = -3.4e38f, mn = 3.4e38f;
#pragma unroll 6
  for (int hw = 0; hw < HWO; ++hw) {
    size_t off = base + (size_t)hw * NC;
    float v = p0[off] + p1[off];
    s += v; sq += v * v;
    mx = fmaxf(mx, v); mn = fminf(mn, v);
  }
  int o = bt * NC + c;
  sarr[o] = s; sqarr[o] = sq; mxarr[o] = mx; mnarr[o] = mn;
}

// ---------------- 4b) BN finalize, two-stage ----------------
__global__ __launch_bounds__(384)
void bn_finA(const float* __restrict__ sarr, const float* __restrict__ sqarr,
             float* __restrict__ partA) {
  int c = threadIdx.x;
  int b0 = blockIdx.x * 16;
  float s = 0.f, sq = 0.f;
#pragma unroll
  for (int i = 0; i < 16; ++i) {
    s += sarr[(b0 + i) * NC + c];
    sq += sqarr[(b0 + i) * NC + c];
  }
  partA[blockIdx.x * 768 + c] = s;
  partA[blockIdx.x * 768 + 384 + c] = sq;
}

__global__ __launch_bounds__(384)
void bn_finB(const float* __restrict__ partA, const float* __restrict__ bn_g,
             const float* __restrict__ bn_b, float* __restrict__ bnsc,
             float* __restrict__ bnsh) {
  int c = threadIdx.x;
  float s = 0.f, sq = 0.f;
#pragma unroll
  for (int i = 0; i < 32; ++i) {
    s += partA[i * 768 + c];
    sq += partA[i * 768 + 384 + c];
  }
  float mean = s / (float)MCONV;
  float var = sq / (float)MCONV - mean * mean;
  float sc = bn_g[c] / sqrtf(var + 1e-5f);
  bnsc[c] = sc;
  bnsh[c] = bn_b[c] - mean * sc;
}

// ---------------- 5) LayerNorm over pooled features (tiny reads) ----------------
__global__ __launch_bounds__(384)
void pool_ln(const float* __restrict__ sarr, const float* __restrict__ mxarr,
             const float* __restrict__ mnarr,
             const float* __restrict__ bnsc, const float* __restrict__ bnsh,
             const float* __restrict__ ln_g, const float* __restrict__ ln_b,
             float* __restrict__ y) {
  __shared__ float r1[6], r2[6], stats[2];
  int bt = blockIdx.x, c = threadIdx.x;
  int o = bt * NC + c;
  float sc = bnsc[c], sh = bnsh[c];
  float meanv = sarr[o] * (1.f / 36.f) * sc + sh;
  float mxv = (sc >= 0.f ? mxarr[o] : mnarr[o]) * sc + sh;
  float v1 = meanv + mxv;
  float v2 = meanv * meanv + mxv * mxv;
#pragma unroll
  for (int off = 32; off; off >>= 1) {
    v1 += __shfl_down(v1, off, 64);
    v2 += __shfl_down(v2, off, 64);
  }
  if ((c & 63) == 0) { r1[c >> 6] = v1; r2[c >> 6] = v2; }
  __syncthreads();
  if (c == 0) {
    float S1 = 0.f, S2 = 0.f;
#pragma unroll
    for (int i = 0; i < 6; ++i) { S1 += r1[i]; S2 += r2[i]; }
    float mu = S1 / (float)C2;
    float var = S2 / (float)C2 - mu * mu;
    stats[0] = mu;
    stats[1] = 1.0f / sqrtf(var + 1e-5f);
  }
  __syncthreads();
  float mu = stats[0], rstd = stats[1];
  y[(size_t)bt * C2 + c] = (meanv - mu) * rstd * ln_g[c] + ln_b[c];
  y[(size_t)bt * C2 + 384 + c] = (mxv - mu) * rstd * ln_g[384 + c] + ln_b[384 + c];
}

// ---------------- 6) small fp32 GEMM (+gelu, optional fused x2 build / gmean epilogue) ----------------
template <int GELU, int X2, int GM>
__global__ __launch_bounds__(256)
void gemm64(const float* __restrict__ A, const float* __restrict__ gmv,
            const float* __restrict__ Wm,
            const float* __restrict__ bias, float* __restrict__ Cm,
            int K, int N, float* __restrict__ gmout) {
  __shared__ float As[64][17];
  __shared__ float Bs[16][68];
  __shared__ float gmred[16][64];
  int tid = threadIdx.x;
  int tx = tid & 15, ty = tid >> 4;
  int m0 = blockIdx.y * 64, n0 = blockIdx.x * 64;
  int ar = tid >> 2, ak = (tid & 3) * 4;
  int br = tid >> 4, bc = (tid & 15) * 4;
  float acc[4][4] = {};
  for (int kt = 0; kt < K; kt += 16) {
    int kcol = kt + ak;
    float4 av;
    if (X2 && kcol >= 384)
      av = *(const float4*)(gmv + ((m0 + ar) >> 4) * 384 + (kcol - 384));
    else
      av = *(const float4*)(A + (size_t)(m0 + ar) * K + kcol);
    float4 bv = *(const float4*)(Wm + (size_t)(kt + br) * N + n0 + bc);
    As[ar][ak + 0] = av.x; As[ar][ak + 1] = av.y;
    As[ar][ak + 2] = av.z; As[ar][ak + 3] = av.w;
    Bs[br][bc + 0] = bv.x; Bs[br][bc + 1] = bv.y;
    Bs[br][bc + 2] = bv.z; Bs[br][bc + 3] = bv.w;
    __syncthreads();
#pragma unroll
    for (int kk = 0; kk < 16; ++kk) {
      float a0 = As[ty * 4 + 0][kk], a1 = As[ty * 4 + 1][kk];
      float a2 = As[ty * 4 + 2][kk], a3 = As[ty * 4 + 3][kk];
      float b0 = Bs[kk][tx * 4 + 0], b1 = Bs[kk][tx * 4 + 1];
      float b2 = Bs[kk][tx * 4 + 2], b3 = Bs[kk][tx * 4 + 3];
      acc[0][0] += a0 * b0; acc[0][1] += a0 * b1; acc[0][2] += a0 * b2; acc[0][3] += a0 * b3;
      acc[1][0] += a1 * b0; acc[1][1] += a1 * b1; acc[1][2] += a1 * b2; acc[1][3] += a1 * b3;
      acc[2][0] += a2 * b0; acc[2][1] += a2 * b1; acc[2][2] += a2 * b2; acc[2][3] += a2 * b3;
      acc[3][0] += a3 * b0; acc[3][1] += a3 * b1; acc[3][2] += a3 * b2; acc[3][3] += a3 * b3;
    }
    __syncthreads();
  }
  float vout[4][4];
#pragma unroll
  for (int i = 0; i < 4; ++i) {
    int row = m0 + ty * 4 + i;
#pragma unroll
    for (int j = 0; j < 4; ++j) {
      int col = n0 + tx * 4 + j;
      float v = acc[i][j] + bias[col];
      if (GELU) v = 0.5f * v * (1.0f + erff(v * 0.70710678118654752f));
      vout[i][j] = v;
      Cm[(size_t)row * N + col] = v;
    }
  }
  if (GM && n0 >= 384) {
#pragma unroll
    for (int j = 0; j < 4; ++j)
      gmred[ty][tx * 4 + j] = vout[0][j] + vout[1][j] + vout[2][j] + vout[3][j];
    __syncthreads();
    int b_l = tid >> 6, col = tid & 63;
    float g = (gmred[b_l * 4 + 0][col] + gmred[b_l * 4 + 1][col] +
               gmred[b_l * 4 + 2][col] + gmred[b_l * 4 + 3][col]) * (1.f / 16.f);
    gmout[(blockIdx.y * 4 + b_l) * 384 + (n0 - 384) + col] = g;
  }
}

// ---------------- 9) score head: 8 sample-chunks per b, per-chunk counts ----------------
__global__ __launch_bounds__(256)
void score_head(const float* __restrict__ h2, const float* __restrict__ w3,
                const float* __restrict__ b3, const float* __restrict__ noise,
                unsigned* __restrict__ pcnt, float* __restrict__ out_inds) {
  int b = blockIdx.x >> 3, chunk = blockIdx.x & 7;
  int tid = threadIdx.x;
  int lane = tid & 63, wv = tid >> 6;
  __shared__ float sv[16], sn[16];
  __shared__ unsigned cnt[256];
  for (int t = wv; t < 16; t += 4) {
    const float* hr = h2 + ((size_t)b * 16 + t) * 192;
    float p = 0.f;
    for (int i = lane; i < 192; i += 64) p += hr[i] * w3[i];
#pragma unroll
    for (int off = 32; off; off >>= 1) p += __shfl_down(p, off, 64);
    if (lane == 0) sv[t] = p + b3[0];
  }
  cnt[tid] = 0;
  __syncthreads();
  if (tid == 0) {
    float mn = sv[0], mx = sv[0];
    for (int t = 1; t < 16; ++t) { mn = fminf(mn, sv[t]); mx = fmaxf(mx, sv[t]); }
    float inv = 1.0f / (mx - mn + 1e-5f);
    for (int t = 0; t < 16; ++t) sn[t] = (sv[t] - mn) * inv;
  }
  __syncthreads();
  if (chunk == 0 && tid < 16) {
    int t = tid, r = 0;
    for (int u = 0; u < 16; ++u)
      r += (sv[u] < sv[t]) || (sv[u] == sv[t] && u < t);
    out_inds[b * 16 + r] = (float)t;
  }
  if (tid < 125) {
    int s = chunk * 125 + tid;
    const float* nz = noise + ((size_t)b * NSAMP + s) * 16;
    float pert[16];
#pragma unroll
    for (int t = 0; t < 16; ++t) pert[t] = sn[t] + 0.05f * nz[t];
    unsigned tm = 0, bm2 = 0;
#pragma unroll
    for (int t = 0; t < 16; ++t) {
      int ct = 0, cb = 0;
#pragma unroll
      for (int u = 0; u < 16; ++u) {
        ct += (pert[u] > pert[t]) || (pert[u] == pert[t] && u < t);
        cb += (pert[u] < pert[t]) || (pert[u] == pert[t] && u < t);
      }
      if (ct < 8) tm |= 1u << t;
      if (cb < 8) bm2 |= 1u << t;
    }
    int j = 0, jb = 0;
#pragma unroll
    for (int t = 0; t < 16; ++t) {
      if (tm & (1u << t)) { if (j < 8) atomicAdd(&cnt[j * 16 + t], 1u); ++j; }
      if (bm2 & (1u << t)) { if (jb < 8) atomicAdd(&cnt[128 + jb * 16 + t], 1u); ++jb; }
    }
  }
  __syncthreads();
  pcnt[(size_t)(b * 8 + chunk) * 256 + tid] = cnt[tid];
}

// ---------------- 10) weighted gather of frames (float4), sums 8 count-chunks ----------------
__global__ __launch_bounds__(256)
void gather_k(const float* __restrict__ frames, const unsigned* __restrict__ pcnt,
              float* __restrict__ out) {
  int bid = blockIdx.x;             // 4 (b,c) pairs per block; same b (384%4==0)
  int tid = threadIdx.x;
  int b = (bid * 4) / NC;
  __shared__ float wt[256];
  {
    unsigned s = 0;
    const unsigned* pc = pcnt + (size_t)b * 8 * 256 + tid;
#pragma unroll
    for (int ch = 0; ch < 8; ++ch) s += pc[ch * 256];
    wt[tid] = (float)s / 1000.0f;
  }
  __syncthreads();
  if (tid >= 196) return;
  int cc = tid / 49, q = tid - cc * 49;
  int bc = bid * 4 + cc;
  const float4* src = (const float4*)(frames + (size_t)bc * NT * HWI) + q;
  float4 v[16];
#pragma unroll
  for (int t = 0; t < 16; ++t) v[t] = src[t * 49];
  float4* o1 = (float4*)(out + (size_t)bc * TOPK * HWI) + q;
  float4* o2 = (float4*)(out + OUT_TOPK_ELEMS + (size_t)bc * TOPK * HWI) + q;
#pragma unroll
  for (int k = 0; k < TOPK; ++k) {
    float4 st = {0.f, 0.f, 0.f, 0.f}, sb = {0.f, 0.f, 0.f, 0.f};
#pragma unroll
    for (int t = 0; t < 16; ++t) {
      float a = wt[k * 16 + t], bw = wt[128 + k * 16 + t];
      st.x += a * v[t].x; st.y += a * v[t].y; st.z += a * v[t].z; st.w += a * v[t].w;
      sb.x += bw * v[t].x; sb.y += bw * v[t].y; sb.z += bw * v[t].z; sb.w += bw * v[t].w;
    }
    o1[k * 49] = st;
    o2[k * 49] = sb;
  }
}

// ---------------- launcher ----------------
extern "C" void kernel_launch(void* const* d_in, const int* in_sizes, int n_in,
                              void* d_out, int out_size, void* d_ws, size_t ws_size,
                              hipStream_t stream) {
  const float* frames = (const float*)d_in[0];
  const float* noise  = (const float*)d_in[1];
  const float* conv_w = (const float*)d_in[2];
  const float* conv_b = (const float*)d_in[3];
  const float* bn_g   = (const float*)d_in[4];
  const float* bn_b   = (const float*)d_in[5];
  const float* ln_g   = (const float*)d_in[6];
  const float* ln_b   = (const float*)d_in[7];
  const float* lin_w  = (const float*)d_in[8];
  const float* lin_b  = (const float*)d_in[9];
  const float* w1     = (const float*)d_in[10];
  const float* b1     = (const float*)d_in[11];
  const float* w2     = (const float*)d_in[12];
  const float* b2     = (const float*)d_in[13];
  const float* w3     = (const float*)d_in[14];
  const float* b3     = (const float*)d_in[15];

  char* ws = (char*)d_ws;
  unsigned short* fhi = (unsigned short*)(ws + OFF_FHI);
  unsigned short* flo = (unsigned short*)(ws + OFF_FLO);
  unsigned short* whi = (unsigned short*)(ws + OFF_WHI);
  unsigned short* wlo = (unsigned short*)(ws + OFF_WLO);
  float* p0    = (float*)(ws + OFF_CONV);
  float* sarr  = (float*)(ws + OFF_SARR);
  float* sqarr = (float*)(ws + OFF_SQAR);
  float* mxarr = (float*)(ws + OFF_MXAR);
  float* mnarr = (float*)(ws + OFF_MNAR);
  float* bnsc  = (float*)(ws + OFF_BNSC);
  float* bnsh  = (float*)(ws + OFF_BNSH);
  float* y     = (float*)(ws + OFF_Y);
  float* x1    = (float*)(ws + OFF_X1);
  float* gm    = (float*)(ws + OFF_GM);
  float* h1    = (float*)(ws + OFF_H1);
  float* h2    = (float*)(ws + OFF_H2);
  unsigned* pcnt = (unsigned*)(ws + OFF_PCNT);
  float* partA = (float*)(ws + OFF_PARTA);
  float* out   = (float*)d_out;
  // p1 scratch lives in d_out (extent 7.1M floats < inds offset 38.5M);
  // gather_k overwrites it later on the same serial stream.
  float* p1    = out;

  split_all<<<3456, 256, 0, stream>>>(frames, conv_w, fhi, flo, whi, wlo);
  conv_gemm<<<864, 256, 0, stream>>>(fhi, flo, whi, wlo, conv_b, p0, p1);
  reduce_all<<<512, 384, 0, stream>>>(p0, p1, sarr, sqarr, mxarr, mnarr);
  bn_finA<<<32, 384, 0, stream>>>(sarr, sqarr, partA);
  bn_finB<<<1, 384, 0, stream>>>(partA, bn_g, bn_b, bnsc, bnsh);
  pool_ln<<<512, 384, 0, stream>>>(sarr, mxarr, mnarr, bnsc, bnsh, ln_g, ln_b, y);
  gemm64<1, 0, 1><<<dim3(12, 8), 256, 0, stream>>>(y, nullptr, lin_w, lin_b, x1, 768, 768, gm);
  gemm64<1, 1, 0><<<dim3(6, 8), 256, 0, stream>>>(x1, gm, w1, b1, h1, 768, 384, nullptr);
  gemm64<1, 0, 0><<<dim3(3, 8), 256, 0, stream>>>(h1, nullptr, w2, b2, h2, 384, 192, nullptr);
  score_head<<<256, 256, 0, stream>>>(h2, w3, b3, noise, pcnt, out + OUT_INDS_OFF);
  gather_k<<<3072, 256, 0, stream>>>(frames, pcnt, out);
}

// Round 10
// 466.085 us; speedup vs baseline: 1.0985x; 1.0165x over previous
//
#include <hip/hip_runtime.h>
#include <hip/hip_bf16.h>
#include <cstdint>

// ---------------- problem constants ----------------
#define NB 32
#define NC 384
#define NT 16
#define NH 14
#define NW 14
#define HWI 196          // 14*14
#define HOW 6            // conv out H,W
#define HWO 36           // 6*6
#define C2 768
#define MCONV (NB*NT*HWO)   // 18432
#define KCONV 3456          // 384*9
#define TOPK 8
#define NSAMP 1000
#define OUT_TOPK_ELEMS (NB*NC*TOPK*HWI)  // 19267584
#define OUT_INDS_OFF   (2*OUT_TOPK_ELEMS) // 38535168
#define PELEMS (MCONV*NC)                 // 7077888 per partial

// ---------------- ws layout (bytes) ----------------
#define OFF_FHI  0ull
#define OFF_FLO  77070336ull
#define OFF_WHI  154140672ull
#define OFF_WLO  156794880ull
#define OFF_CONV 159449088ull
// region A overlays FHI after conv is done (written only post-conv):
#define OFF_SARR 0ull            // 512*384*4 = 786432
#define OFF_SQAR 786432ull
#define OFF_MXAR 1572864ull
#define OFF_MNAR 2359296ull
#define OFF_BNSC 3145728ull
#define OFF_BNSH 3147264ull
#define OFF_Y    3148800ull      // 512*768*4 = 1572864
#define OFF_X1   4721664ull
#define OFF_GM   6294528ull      // 49152
#define OFF_H1   6343680ull      // 786432
#define OFF_H2   7130112ull      // 393216
#define OFF_PCNT 7523328ull      // 32*8*256*4 = 262144
#define OFF_PARTA 7785472ull     // 32*768*4 = 98304

typedef __attribute__((ext_vector_type(4))) float f32x4;
typedef __attribute__((ext_vector_type(8))) short bf16x8;

__device__ __forceinline__ unsigned short f2bf(float f) {
  unsigned u = __float_as_uint(f);
  unsigned r = (u + 0x7FFFu + ((u >> 16) & 1u)) >> 16;  // RN-even
  return (unsigned short)r;
}
__device__ __forceinline__ float bf2f(unsigned short u) {
  return __uint_as_float(((unsigned)u) << 16);
}

__device__ __forceinline__ void gload_lds16(const void* gptr, void* lptr) {
  __builtin_amdgcn_global_load_lds(
      (const __attribute__((address_space(1))) unsigned int*)gptr,
      (__attribute__((address_space(3))) unsigned int*)lptr, 16, 0, 0);
}

// ---------------- 1) fused: frames -> (b,t,hw,c) bf16 hi/lo  AND  conv_w transpose ----------------
__global__ __launch_bounds__(256)
void split_all(const float* __restrict__ fr, const float* __restrict__ cw,
               unsigned short* __restrict__ fhi, unsigned short* __restrict__ flo,
               unsigned short* __restrict__ whi, unsigned short* __restrict__ wlo) {
  __shared__ char smem[64 * 197 * 4];
  int bid = blockIdx.x;
  if (bid < 3072) {
    unsigned int (*tile)[197] = (unsigned int (*)[197])smem;
    int cb = bid % 6, bt = bid / 6;
    int b = bt >> 4, t = bt & 15;
    const float* src = fr + (((size_t)b * NC + cb * 64) * NT + t) * HWI;
    for (int i = threadIdx.x; i < 64 * 49; i += 256) {
      int c = i / 49, q = i - c * 49;
      float4 v = *(const float4*)(src + (size_t)c * (NT * HWI) + q * 4);
      float vv[4] = {v.x, v.y, v.z, v.w};
#pragma unroll
      for (int u = 0; u < 4; ++u) {
        unsigned short h = f2bf(vv[u]);
        unsigned short l = f2bf(vv[u] - bf2f(h));
        tile[c][q * 4 + u] = ((unsigned)h << 16) | (unsigned)l;
      }
    }
    __syncthreads();
    size_t obase = ((size_t)bt * HWI) * NC + cb * 64;
    for (int i = threadIdx.x; i < 196 * 8; i += 256) {
      int hw = i >> 3, c8 = i & 7;
      bf16x8 vh, vl;
#pragma unroll
      for (int u = 0; u < 8; ++u) {
        unsigned p = tile[c8 * 8 + u][hw];
        vh[u] = (short)(p >> 16);
        vl[u] = (short)(p & 0xffff);
      }
      size_t o = obase + (size_t)hw * NC + c8 * 8;
      *(bf16x8*)(fhi + o) = vh;
      *(bf16x8*)(flo + o) = vl;
    }
  } else {
    float* t = (float*)smem;
    int co = bid - 3072;
    const float* src = cw + (size_t)co * KCONV;
    for (int i = threadIdx.x; i < KCONV / 4; i += 256)
      *(float4*)&t[i * 4] = *(const float4*)&src[i * 4];
    __syncthreads();
    unsigned short* oh = whi + (size_t)co * KCONV;
    unsigned short* ol = wlo + (size_t)co * KCONV;
    for (int i = threadIdx.x; i < KCONV; i += 256) {
      int c9 = i / NC, ci = i - c9 * NC;
      float v = t[ci * 9 + c9];
      unsigned short h = f2bf(v);
      oh[i] = h; ol[i] = f2bf(v - bf2f(h));
    }
  }
}

// ---------------- 3) conv implicit GEMM, split-bf16 3-product, split-K=2, swizzled LDS ----------------
// LDS swizzle verified conflict-free (R4: SQ_LDS_BANK_CONFLICT=0).
// Linear block decode (R5/R7 A/B: linear 174 vs XCD 187 — keep linear).
// Split-K=2 (R4/R9-measured): best total-time tradeoff vs K=4's +113MB partial traffic.
__global__ __launch_bounds__(256, 4)
void conv_gemm(const unsigned short* __restrict__ fhi,
               const unsigned short* __restrict__ flo,
               const unsigned short* __restrict__ whi,
               const unsigned short* __restrict__ wlo,
               const float* __restrict__ conv_b,
               float* __restrict__ p0, float* __restrict__ p1) {
  __shared__ unsigned short sAhi[128 * 32], sAlo[128 * 32];
  __shared__ unsigned short sBhi[128 * 32], sBlo[128 * 32];
  const int tid = threadIdx.x;
  const int lane = tid & 63;
  const int wv = tid >> 6;
  const int bid = blockIdx.x;
  const int bm = bid % 144;
  const int r  = bid / 144;        // 0..5
  const int bn = r % 3;
  const int kz = r / 3;            // 0..1

  int aoff[2], boff[2];
#pragma unroll
  for (int j = 0; j < 2; ++j) {
    int l = (wv * 2 + j) * 64 + lane;
    int row = l >> 2;
    int chunk = (l & 3) ^ ((l >> 3) & 3);   // swizzled source chunk
    int m = bm * 128 + row;
    int wo = m % 6; int tmp = m / 6;
    int ho = tmp % 6; tmp /= 6;     // tmp = b*16+t
    aoff[j] = ((tmp * HWI) + (2 * ho) * NW + 2 * wo) * NC + chunk * 8;
    int co = bn * 128 + row;
    boff[j] = co * KCONV + chunk * 8;
  }

  f32x4 acc[4][4];
#pragma unroll
  for (int i = 0; i < 4; ++i)
#pragma unroll
    for (int j = 0; j < 4; ++j) acc[i][j] = (f32x4){0.f, 0.f, 0.f, 0.f};

  const int wrow = (wv >> 1) * 64;
  const int wcol = (wv & 1) * 64;
  const int fr_row = lane & 15;
  const int slot8 = (((lane >> 4) ^ ((fr_row >> 1) & 3))) * 8;

  int c9  = kz ? 4 : 0;
  int rem = kz ? 6 : 0;
  for (int s = 0; s < 54; ++s) {
    int kh = c9 / 3, kw = c9 - kh * 3;
    int soffA = (kh * NW + kw) * NC + rem * 32;
    int soffB = c9 * NC + rem * 32;
#pragma unroll
    for (int j = 0; j < 2; ++j) {
      char* ldsA  = (char*)sAhi + (wv * 2 + j) * 1024;
      char* ldsAl = (char*)sAlo + (wv * 2 + j) * 1024;
      char* ldsB  = (char*)sBhi + (wv * 2 + j) * 1024;
      char* ldsBl = (char*)sBlo + (wv * 2 + j) * 1024;
      gload_lds16(fhi + aoff[j] + soffA, ldsA);
      gload_lds16(flo + aoff[j] + soffA, ldsAl);
      gload_lds16(whi + boff[j] + soffB, ldsB);
      gload_lds16(wlo + boff[j] + soffB, ldsBl);
    }
    __syncthreads();
    bf16x8 ah[4], al[4], bh[4], bl[4];
#pragma unroll
    for (int m = 0; m < 4; ++m) {
      int rr = wrow + m * 16 + fr_row;
      ah[m] = *(const bf16x8*)&sAhi[rr * 32 + slot8];
      al[m] = *(const bf16x8*)&sAlo[rr * 32 + slot8];
    }
#pragma unroll
    for (int n = 0; n < 4; ++n) {
      int rr = wcol + n * 16 + fr_row;
      bh[n] = *(const bf16x8*)&sBhi[rr * 32 + slot8];
      bl[n] = *(const bf16x8*)&sBlo[rr * 32 + slot8];
    }
#pragma unroll
    for (int m = 0; m < 4; ++m)
#pragma unroll
      for (int n = 0; n < 4; ++n) {
        acc[m][n] = __builtin_amdgcn_mfma_f32_16x16x32_bf16(ah[m], bh[n], acc[m][n], 0, 0, 0);
        acc[m][n] = __builtin_amdgcn_mfma_f32_16x16x32_bf16(ah[m], bl[n], acc[m][n], 0, 0, 0);
        acc[m][n] = __builtin_amdgcn_mfma_f32_16x16x32_bf16(al[m], bh[n], acc[m][n], 0, 0, 0);
      }
    __syncthreads();
    if (++rem == 12) { rem = 0; ++c9; }
  }

  float* dst = kz ? p1 : p0;
#pragma unroll
  for (int m = 0; m < 4; ++m)
#pragma unroll
    for (int n = 0; n < 4; ++n) {
      int col = bn * 128 + wcol + n * 16 + (lane & 15);
      float cb = kz ? 0.f : conv_b[col];
#pragma unroll
      for (int j = 0; j < 4; ++j) {
        int row = bm * 128 + wrow + m * 16 + (lane >> 4) * 4 + j;
        dst[(size_t)row * NC + col] = acc[m][n][j] + cb;
      }
    }
}

// ---------------- 4) fused reduce: BN partial stats + pool sum/max/min per (bt,c) ----------------
__global__ __launch_bounds__(384)
void reduce_all(const float* __restrict__ p0, const float* __restrict__ p1,
                float* __restrict__ sarr, float* __restrict__ sqarr,
                float* __restrict__ mxarr, float* __restrict__ mnarr) {
  int bt = blockIdx.x, c = threadIdx.x;
  size_t base = (size_t)bt * HWO * NC + c;
  float s = 0.f, sq = 0.f, mx = -3.4e38f, mn = 3.4e38f;
#pragma unroll 6
  for (int hw = 0; hw < HWO; ++hw) {
    size_t off = base + (size_t)hw * NC;
    float v = p0[off] + p1[off];
    s += v; sq += v * v;
    mx = fmaxf(mx, v); mn = fminf(mn, v);
  }
  int o = bt * NC + c;
  sarr[o] = s; sqarr[o] = sq; mxarr[o] = mx; mnarr[o] = mn;
}

// ---------------- 4b) BN finalize, two-stage ----------------
__global__ __launch_bounds__(384)
void bn_finA(const float* __restrict__ sarr, const float* __restrict__ sqarr,
             float* __restrict__ partA) {
  int c = threadIdx.x;
  int b0 = blockIdx.x * 16;
  float s = 0.f, sq = 0.f;
#pragma unroll
  for (int i = 0; i < 16; ++i) {
    s += sarr[(b0 + i) * NC + c];
    sq += sqarr[(b0 + i) * NC + c];
  }
  partA[blockIdx.x * 768 + c] = s;
  partA[blockIdx.x * 768 + 384 + c] = sq;
}

__global__ __launch_bounds__(384)
void bn_finB(const float* __restrict__ partA, const float* __restrict__ bn_g,
             const float* __restrict__ bn_b, float* __restrict__ bnsc,
             float* __restrict__ bnsh) {
  int c = threadIdx.x;
  float s = 0.f, sq = 0.f;
#pragma unroll
  for (int i = 0; i < 32; ++i) {
    s += partA[i * 768 + c];
    sq += partA[i * 768 + 384 + c];
  }
  float mean = s / (float)MCONV;
  float var = sq / (float)MCONV - mean * mean;
  float sc = bn_g[c] / sqrtf(var + 1e-5f);
  bnsc[c] = sc;
  bnsh[c] = bn_b[c] - mean * sc;
}

// ---------------- 5) LayerNorm over pooled features (tiny reads) ----------------
__global__ __launch_bounds__(384)
void pool_ln(const float* __restrict__ sarr, const float* __restrict__ mxarr,
             const float* __restrict__ mnarr,
             const float* __restrict__ bnsc, const float* __restrict__ bnsh,
             const float* __restrict__ ln_g, const float* __restrict__ ln_b,
             float* __restrict__ y) {
  __shared__ float r1[6], r2[6], stats[2];
  int bt = blockIdx.x, c = threadIdx.x;
  int o = bt * NC + c;
  float sc = bnsc[c], sh = bnsh[c];
  float meanv = sarr[o] * (1.f / 36.f) * sc + sh;
  float mxv = (sc >= 0.f ? mxarr[o] : mnarr[o]) * sc + sh;
  float v1 = meanv + mxv;
  float v2 = meanv * meanv + mxv * mxv;
#pragma unroll
  for (int off = 32; off; off >>= 1) {
    v1 += __shfl_down(v1, off, 64);
    v2 += __shfl_down(v2, off, 64);
  }
  if ((c & 63) == 0) { r1[c >> 6] = v1; r2[c >> 6] = v2; }
  __syncthreads();
  if (c == 0) {
    float S1 = 0.f, S2 = 0.f;
#pragma unroll
    for (int i = 0; i < 6; ++i) { S1 += r1[i]; S2 += r2[i]; }
    float mu = S1 / (float)C2;
    float var = S2 / (float)C2 - mu * mu;
    stats[0] = mu;
    stats[1] = 1.0f / sqrtf(var + 1e-5f);
  }
  __syncthreads();
  float mu = stats[0], rstd = stats[1];
  y[(size_t)bt * C2 + c] = (meanv - mu) * rstd * ln_g[c] + ln_b[c];
  y[(size_t)bt * C2 + 384 + c] = (mxv - mu) * rstd * ln_g[384 + c] + ln_b[384 + c];
}

// ---------------- 6) small fp32 GEMM, 32x64 tiles (2x grid vs 64x64 for latency-bound sizes) ----------------
template <int GELU, int X2, int GM>
__global__ __launch_bounds__(256)
void gemm32(const float* __restrict__ A, const float* __restrict__ gmv,
            const float* __restrict__ Wm,
            const float* __restrict__ bias, float* __restrict__ Cm,
            int K, int N, float* __restrict__ gmout) {
  __shared__ float As[32][17];
  __shared__ float Bs[16][68];
  __shared__ float gmred[16][64];
  int tid = threadIdx.x;
  int tx = tid & 15, ty = tid >> 4;         // ty: 16 groups of 2 rows
  int m0 = blockIdx.y * 32, n0 = blockIdx.x * 64;
  int br = tid >> 4, bc = (tid & 15) * 4;
  float acc[2][4] = {};
  for (int kt = 0; kt < K; kt += 16) {
    if (tid < 128) {
      int ar = tid >> 2, ak = (tid & 3) * 4;
      int kcol = kt + ak;
      float4 av;
      if (X2 && kcol >= 384)
        av = *(const float4*)(gmv + ((m0 + ar) >> 4) * 384 + (kcol - 384));
      else
        av = *(const float4*)(A + (size_t)(m0 + ar) * K + kcol);
      As[ar][ak + 0] = av.x; As[ar][ak + 1] = av.y;
      As[ar][ak + 2] = av.z; As[ar][ak + 3] = av.w;
    }
    float4 bv = *(const float4*)(Wm + (size_t)(kt + br) * N + n0 + bc);
    Bs[br][bc + 0] = bv.x; Bs[br][bc + 1] = bv.y;
    Bs[br][bc + 2] = bv.z; Bs[br][bc + 3] = bv.w;
    __syncthreads();
#pragma unroll
    for (int kk = 0; kk < 16; ++kk) {
      float a0 = As[ty * 2 + 0][kk], a1 = As[ty * 2 + 1][kk];
      float b0 = Bs[kk][tx * 4 + 0], b1 = Bs[kk][tx * 4 + 1];
      float b2 = Bs[kk][tx * 4 + 2], b3 = Bs[kk][tx * 4 + 3];
      acc[0][0] += a0 * b0; acc[0][1] += a0 * b1; acc[0][2] += a0 * b2; acc[0][3] += a0 * b3;
      acc[1][0] += a1 * b0; acc[1][1] += a1 * b1; acc[1][2] += a1 * b2; acc[1][3] += a1 * b3;
    }
    __syncthreads();
  }
  float vout[2][4];
#pragma unroll
  for (int i = 0; i < 2; ++i) {
    int row = m0 + ty * 2 + i;
#pragma unroll
    for (int j = 0; j < 4; ++j) {
      int col = n0 + tx * 4 + j;
      float v = acc[i][j] + bias[col];
      if (GELU) v = 0.5f * v * (1.0f + erff(v * 0.70710678118654752f));
      vout[i][j] = v;
      Cm[(size_t)row * N + col] = v;
    }
  }
  if (GM && n0 >= 384) {
    // block covers rows m0..m0+31 = 2 b-groups of 16 t rows each
#pragma unroll
    for (int j = 0; j < 4; ++j)
      gmred[ty][tx * 4 + j] = vout[0][j] + vout[1][j];
    __syncthreads();
    if (tid < 128) {
      int b_l = tid >> 6, col = tid & 63;   // b_l: 0..1
      float g = 0.f;
#pragma unroll
      for (int i = 0; i < 8; ++i) g += gmred[b_l * 8 + i][col];
      gmout[(blockIdx.y * 2 + b_l) * 384 + (n0 - 384) + col] = g * (1.f / 16.f);
    }
  }
}

// ---------------- 9) score head: 8 sample-chunks per b, per-chunk counts ----------------
__global__ __launch_bounds__(256)
void score_head(const float* __restrict__ h2, const float* __restrict__ w3,
                const float* __restrict__ b3, const float* __restrict__ noise,
                unsigned* __restrict__ pcnt, float* __restrict__ out_inds) {
  int b = blockIdx.x >> 3, chunk = blockIdx.x & 7;
  int tid = threadIdx.x;
  int lane = tid & 63, wv = tid >> 6;
  __shared__ float sv[16], sn[16];
  __shared__ unsigned cnt[256];
  for (int t = wv; t < 16; t += 4) {
    const float* hr = h2 + ((size_t)b * 16 + t) * 192;
    float p = 0.f;
    for (int i = lane; i < 192; i += 64) p += hr[i] * w3[i];
#pragma unroll
    for (int off = 32; off; off >>= 1) p += __shfl_down(p, off, 64);
    if (lane == 0) sv[t] = p + b3[0];
  }
  cnt[tid] = 0;
  __syncthreads();
  if (tid == 0) {
    float mn = sv[0], mx = sv[0];
    for (int t = 1; t < 16; ++t) { mn = fminf(mn, sv[t]); mx = fmaxf(mx, sv[t]); }
    float inv = 1.0f / (mx - mn + 1e-5f);
    for (int t = 0; t < 16; ++t) sn[t] = (sv[t] - mn) * inv;
  }
  __syncthreads();
  if (chunk == 0 && tid < 16) {
    int t = tid, r = 0;
    for (int u = 0; u < 16; ++u)
      r += (sv[u] < sv[t]) || (sv[u] == sv[t] && u < t);
    out_inds[b * 16 + r] = (float)t;
  }
  if (tid < 125) {
    int s = chunk * 125 + tid;
    const float* nz = noise + ((size_t)b * NSAMP + s) * 16;
    float pert[16];
#pragma unroll
    for (int t = 0; t < 16; ++t) pert[t] = sn[t] + 0.05f * nz[t];
    unsigned tm = 0, bm2 = 0;
#pragma unroll
    for (int t = 0; t < 16; ++t) {
      int ct = 0, cb = 0;
#pragma unroll
      for (int u = 0; u < 16; ++u) {
        ct += (pert[u] > pert[t]) || (pert[u] == pert[t] && u < t);
        cb += (pert[u] < pert[t]) || (pert[u] == pert[t] && u < t);
      }
      if (ct < 8) tm |= 1u << t;
      if (cb < 8) bm2 |= 1u << t;
    }
    int j = 0, jb = 0;
#pragma unroll
    for (int t = 0; t < 16; ++t) {
      if (tm & (1u << t)) { if (j < 8) atomicAdd(&cnt[j * 16 + t], 1u); ++j; }
      if (bm2 & (1u << t)) { if (jb < 8) atomicAdd(&cnt[128 + jb * 16 + t], 1u); ++jb; }
    }
  }
  __syncthreads();
  pcnt[(size_t)(b * 8 + chunk) * 256 + tid] = cnt[tid];
}

// ---------------- 10) weighted gather of frames (float4), sums 8 count-chunks ----------------
__global__ __launch_bounds__(256)
void gather_k(const float* __restrict__ frames, const unsigned* __restrict__ pcnt,
              float* __restrict__ out) {
  int bid = blockIdx.x;             // 4 (b,c) pairs per block; same b (384%4==0)
  int tid = threadIdx.x;
  int b = (bid * 4) / NC;
  __shared__ float wt[256];
  {
    unsigned s = 0;
    const unsigned* pc = pcnt + (size_t)b * 8 * 256 + tid;
#pragma unroll
    for (int ch = 0; ch < 8; ++ch) s += pc[ch * 256];
    wt[tid] = (float)s / 1000.0f;
  }
  __syncthreads();
  if (tid >= 196) return;
  int cc = tid / 49, q = tid - cc * 49;
  int bc = bid * 4 + cc;
  const float4* src = (const float4*)(frames + (size_t)bc * NT * HWI) + q;
  float4 v[16];
#pragma unroll
  for (int t = 0; t < 16; ++t) v[t] = src[t * 49];
  float4* o1 = (float4*)(out + (size_t)bc * TOPK * HWI) + q;
  float4* o2 = (float4*)(out + OUT_TOPK_ELEMS + (size_t)bc * TOPK * HWI) + q;
#pragma unroll
  for (int k = 0; k < TOPK; ++k) {
    float4 st = {0.f, 0.f, 0.f, 0.f}, sb = {0.f, 0.f, 0.f, 0.f};
#pragma unroll
    for (int t = 0; t < 16; ++t) {
      float a = wt[k * 16 + t], bw = wt[128 + k * 16 + t];
      st.x += a * v[t].x; st.y += a * v[t].y; st.z += a * v[t].z; st.w += a * v[t].w;
      sb.x += bw * v[t].x; sb.y += bw * v[t].y; sb.z += bw * v[t].z; sb.w += bw * v[t].w;
    }
    o1[k * 49] = st;
    o2[k * 49] = sb;
  }
}

// ---------------- launcher ----------------
extern "C" void kernel_launch(void* const* d_in, const int* in_sizes, int n_in,
                              void* d_out, int out_size, void* d_ws, size_t ws_size,
                              hipStream_t stream) {
  const float* frames = (const float*)d_in[0];
  const float* noise  = (const float*)d_in[1];
  const float* conv_w = (const float*)d_in[2];
  const float* conv_b = (const float*)d_in[3];
  const float* bn_g   = (const float*)d_in[4];
  const float* bn_b   = (const float*)d_in[5];
  const float* ln_g   = (const float*)d_in[6];
  const float* ln_b   = (const float*)d_in[7];
  const float* lin_w  = (const float*)d_in[8];
  const float* lin_b  = (const float*)d_in[9];
  const float* w1     = (const float*)d_in[10];
  const float* b1     = (const float*)d_in[11];
  const float* w2     = (const float*)d_in[12];
  const float* b2     = (const float*)d_in[13];
  const float* w3     = (const float*)d_in[14];
  const float* b3     = (const float*)d_in[15];

  char* ws = (char*)d_ws;
  unsigned short* fhi = (unsigned short*)(ws + OFF_FHI);
  unsigned short* flo = (unsigned short*)(ws + OFF_FLO);
  unsigned short* whi = (unsigned short*)(ws + OFF_WHI);
  unsigned short* wlo = (unsigned short*)(ws + OFF_WLO);
  float* p0    = (float*)(ws + OFF_CONV);
  float* sarr  = (float*)(ws + OFF_SARR);
  float* sqarr = (float*)(ws + OFF_SQAR);
  float* mxarr = (float*)(ws + OFF_MXAR);
  float* mnarr = (float*)(ws + OFF_MNAR);
  float* bnsc  = (float*)(ws + OFF_BNSC);
  float* bnsh  = (float*)(ws + OFF_BNSH);
  float* y     = (float*)(ws + OFF_Y);
  float* x1    = (float*)(ws + OFF_X1);
  float* gm    = (float*)(ws + OFF_GM);
  float* h1    = (float*)(ws + OFF_H1);
  float* h2    = (float*)(ws + OFF_H2);
  unsigned* pcnt = (unsigned*)(ws + OFF_PCNT);
  float* partA = (float*)(ws + OFF_PARTA);
  float* out   = (float*)d_out;
  // p1 scratch lives in d_out (extent 7.1M floats < inds offset 38.5M);
  // gather_k overwrites it later on the same serial stream.
  float* p1    = out;

  split_all<<<3456, 256, 0, stream>>>(frames, conv_w, fhi, flo, whi, wlo);
  conv_gemm<<<864, 256, 0, stream>>>(fhi, flo, whi, wlo, conv_b, p0, p1);
  reduce_all<<<512, 384, 0, stream>>>(p0, p1, sarr, sqarr, mxarr, mnarr);
  bn_finA<<<32, 384, 0, stream>>>(sarr, sqarr, partA);
  bn_finB<<<1, 384, 0, stream>>>(partA, bn_g, bn_b, bnsc, bnsh);
  pool_ln<<<512, 384, 0, stream>>>(sarr, mxarr, mnarr, bnsc, bnsh, ln_g, ln_b, y);
  gemm32<1, 0, 1><<<dim3(12, 16), 256, 0, stream>>>(y, nullptr, lin_w, lin_b, x1, 768, 768, gm);
  gemm32<1, 1, 0><<<dim3(6, 16), 256, 0, stream>>>(x1, gm, w1, b1, h1, 768, 384, nullptr);
  gemm32<1, 0, 0><<<dim3(3, 16), 256, 0, stream>>>(h1, nullptr, w2, b2, h2, 384, 192, nullptr);
  score_head<<<256, 256, 0, stream>>>(h2, w3, b3, noise, pcnt, out + OUT_INDS_OFF);
  gather_k<<<3072, 256, 0, stream>>>(frames, pcnt, out);
}

// Round 11
// 464.088 us; speedup vs baseline: 1.1032x; 1.0043x over previous
//
#include <hip/hip_runtime.h>
#include <hip/hip_bf16.h>
#include <cstdint>

// ---------------- problem constants ----------------
#define NB 32
#define NC 384
#define NT 16
#define NH 14
#define NW 14
#define HWI 196          // 14*14
#define HOW 6            // conv out H,W
#define HWO 36           // 6*6
#define C2 768
#define MCONV (NB*NT*HWO)   // 18432
#define KCONV 3456          // 384*9
#define TOPK 8
#define NSAMP 1000
#define OUT_TOPK_ELEMS (NB*NC*TOPK*HWI)  // 19267584
#define OUT_INDS_OFF   (2*OUT_TOPK_ELEMS) // 38535168
#define PELEMS (MCONV*NC)                 // 7077888 per partial

// ---------------- ws layout (bytes) ----------------
#define OFF_FHI  0ull
#define OFF_FLO  77070336ull
#define OFF_WHI  154140672ull
#define OFF_WLO  156794880ull
#define OFF_CONV 159449088ull
// region A overlays FHI after conv is done (written only post-conv):
#define OFF_SARR 0ull            // 512*384*4 = 786432
#define OFF_SQAR 786432ull
#define OFF_MXAR 1572864ull
#define OFF_MNAR 2359296ull
#define OFF_Y    3148800ull      // 512*768*4 = 1572864
#define OFF_X1   4721664ull
#define OFF_GM   6294528ull      // 49152
#define OFF_H1   6343680ull      // 786432
#define OFF_H2   7130112ull      // 393216
#define OFF_PCNT 7523328ull      // 32*4*256*4 = 131072
#define OFF_PARTA 7785472ull     // 32*768*4 = 98304

typedef __attribute__((ext_vector_type(4))) float f32x4;
typedef __attribute__((ext_vector_type(8))) short bf16x8;

__device__ __forceinline__ unsigned short f2bf(float f) {
  unsigned u = __float_as_uint(f);
  unsigned r = (u + 0x7FFFu + ((u >> 16) & 1u)) >> 16;  // RN-even
  return (unsigned short)r;
}
__device__ __forceinline__ float bf2f(unsigned short u) {
  return __uint_as_float(((unsigned)u) << 16);
}

__device__ __forceinline__ void gload_lds16(const void* gptr, void* lptr) {
  __builtin_amdgcn_global_load_lds(
      (const __attribute__((address_space(1))) unsigned int*)gptr,
      (__attribute__((address_space(3))) unsigned int*)lptr, 16, 0, 0);
}

// ---------------- 1) fused: frames -> (b,t,hw,c) bf16 hi/lo  AND  conv_w transpose ----------------
__global__ __launch_bounds__(256)
void split_all(const float* __restrict__ fr, const float* __restrict__ cw,
               unsigned short* __restrict__ fhi, unsigned short* __restrict__ flo,
               unsigned short* __restrict__ whi, unsigned short* __restrict__ wlo) {
  __shared__ char smem[64 * 197 * 4];
  int bid = blockIdx.x;
  if (bid < 3072) {
    unsigned int (*tile)[197] = (unsigned int (*)[197])smem;
    int cb = bid % 6, bt = bid / 6;
    int b = bt >> 4, t = bt & 15;
    const float* src = fr + (((size_t)b * NC + cb * 64) * NT + t) * HWI;
    for (int i = threadIdx.x; i < 64 * 49; i += 256) {
      int c = i / 49, q = i - c * 49;
      float4 v = *(const float4*)(src + (size_t)c * (NT * HWI) + q * 4);
      float vv[4] = {v.x, v.y, v.z, v.w};
#pragma unroll
      for (int u = 0; u < 4; ++u) {
        unsigned short h = f2bf(vv[u]);
        unsigned short l = f2bf(vv[u] - bf2f(h));
        tile[c][q * 4 + u] = ((unsigned)h << 16) | (unsigned)l;
      }
    }
    __syncthreads();
    size_t obase = ((size_t)bt * HWI) * NC + cb * 64;
    for (int i = threadIdx.x; i < 196 * 8; i += 256) {
      int hw = i >> 3, c8 = i & 7;
      bf16x8 vh, vl;
#pragma unroll
      for (int u = 0; u < 8; ++u) {
        unsigned p = tile[c8 * 8 + u][hw];
        vh[u] = (short)(p >> 16);
        vl[u] = (short)(p & 0xffff);
      }
      size_t o = obase + (size_t)hw * NC + c8 * 8;
      *(bf16x8*)(fhi + o) = vh;
      *(bf16x8*)(flo + o) = vl;
    }
  } else {
    float* t = (float*)smem;
    int co = bid - 3072;
    const float* src = cw + (size_t)co * KCONV;
    for (int i = threadIdx.x; i < KCONV / 4; i += 256)
      *(float4*)&t[i * 4] = *(const float4*)&src[i * 4];
    __syncthreads();
    unsigned short* oh = whi + (size_t)co * KCONV;
    unsigned short* ol = wlo + (size_t)co * KCONV;
    for (int i = threadIdx.x; i < KCONV; i += 256) {
      int c9 = i / NC, ci = i - c9 * NC;
      float v = t[ci * 9 + c9];
      unsigned short h = f2bf(v);
      oh[i] = h; ol[i] = f2bf(v - bf2f(h));
    }
  }
}

// ---------------- 3) conv implicit GEMM, split-bf16 3-product, split-K=2, swizzled LDS ----------------
// LDS swizzle verified conflict-free (R4: SQ_LDS_BANK_CONFLICT=0).
// Linear block decode (R5/R7 A/B: linear 174 vs XCD 187 — keep linear).
// Split-K=2 (R9/R10-measured): best total-time tradeoff.
__global__ __launch_bounds__(256, 4)
void conv_gemm(const unsigned short* __restrict__ fhi,
               const unsigned short* __restrict__ flo,
               const unsigned short* __restrict__ whi,
               const unsigned short* __restrict__ wlo,
               const float* __restrict__ conv_b,
               float* __restrict__ p0, float* __restrict__ p1) {
  __shared__ unsigned short sAhi[128 * 32], sAlo[128 * 32];
  __shared__ unsigned short sBhi[128 * 32], sBlo[128 * 32];
  const int tid = threadIdx.x;
  const int lane = tid & 63;
  const int wv = tid >> 6;
  const int bid = blockIdx.x;
  const int bm = bid % 144;
  const int r  = bid / 144;        // 0..5
  const int bn = r % 3;
  const int kz = r / 3;            // 0..1

  int aoff[2], boff[2];
#pragma unroll
  for (int j = 0; j < 2; ++j) {
    int l = (wv * 2 + j) * 64 + lane;
    int row = l >> 2;
    int chunk = (l & 3) ^ ((l >> 3) & 3);   // swizzled source chunk
    int m = bm * 128 + row;
    int wo = m % 6; int tmp = m / 6;
    int ho = tmp % 6; tmp /= 6;     // tmp = b*16+t
    aoff[j] = ((tmp * HWI) + (2 * ho) * NW + 2 * wo) * NC + chunk * 8;
    int co = bn * 128 + row;
    boff[j] = co * KCONV + chunk * 8;
  }

  f32x4 acc[4][4];
#pragma unroll
  for (int i = 0; i < 4; ++i)
#pragma unroll
    for (int j = 0; j < 4; ++j) acc[i][j] = (f32x4){0.f, 0.f, 0.f, 0.f};

  const int wrow = (wv >> 1) * 64;
  const int wcol = (wv & 1) * 64;
  const int fr_row = lane & 15;
  const int slot8 = (((lane >> 4) ^ ((fr_row >> 1) & 3))) * 8;

  int c9  = kz ? 4 : 0;
  int rem = kz ? 6 : 0;
  for (int s = 0; s < 54; ++s) {
    int kh = c9 / 3, kw = c9 - kh * 3;
    int soffA = (kh * NW + kw) * NC + rem * 32;
    int soffB = c9 * NC + rem * 32;
#pragma unroll
    for (int j = 0; j < 2; ++j) {
      char* ldsA  = (char*)sAhi + (wv * 2 + j) * 1024;
      char* ldsAl = (char*)sAlo + (wv * 2 + j) * 1024;
      char* ldsB  = (char*)sBhi + (wv * 2 + j) * 1024;
      char* ldsBl = (char*)sBlo + (wv * 2 + j) * 1024;
      gload_lds16(fhi + aoff[j] + soffA, ldsA);
      gload_lds16(flo + aoff[j] + soffA, ldsAl);
      gload_lds16(whi + boff[j] + soffB, ldsB);
      gload_lds16(wlo + boff[j] + soffB, ldsBl);
    }
    __syncthreads();
    bf16x8 ah[4], al[4], bh[4], bl[4];
#pragma unroll
    for (int m = 0; m < 4; ++m) {
      int rr = wrow + m * 16 + fr_row;
      ah[m] = *(const bf16x8*)&sAhi[rr * 32 + slot8];
      al[m] = *(const bf16x8*)&sAlo[rr * 32 + slot8];
    }
#pragma unroll
    for (int n = 0; n < 4; ++n) {
      int rr = wcol + n * 16 + fr_row;
      bh[n] = *(const bf16x8*)&sBhi[rr * 32 + slot8];
      bl[n] = *(const bf16x8*)&sBlo[rr * 32 + slot8];
    }
#pragma unroll
    for (int m = 0; m < 4; ++m)
#pragma unroll
      for (int n = 0; n < 4; ++n) {
        acc[m][n] = __builtin_amdgcn_mfma_f32_16x16x32_bf16(ah[m], bh[n], acc[m][n], 0, 0, 0);
        acc[m][n] = __builtin_amdgcn_mfma_f32_16x16x32_bf16(ah[m], bl[n], acc[m][n], 0, 0, 0);
        acc[m][n] = __builtin_amdgcn_mfma_f32_16x16x32_bf16(al[m], bh[n], acc[m][n], 0, 0, 0);
      }
    __syncthreads();
    if (++rem == 12) { rem = 0; ++c9; }
  }

  float* dst = kz ? p1 : p0;
#pragma unroll
  for (int m = 0; m < 4; ++m)
#pragma unroll
    for (int n = 0; n < 4; ++n) {
      int col = bn * 128 + wcol + n * 16 + (lane & 15);
      float cb = kz ? 0.f : conv_b[col];
#pragma unroll
      for (int j = 0; j < 4; ++j) {
        int row = bm * 128 + wrow + m * 16 + (lane >> 4) * 4 + j;
        dst[(size_t)row * NC + col] = acc[m][n][j] + cb;
      }
    }
}

// ---------------- 4) fused reduce: BN partial stats + pool sum/max/min per (bt,c) ----------------
__global__ __launch_bounds__(384)
void reduce_all(const float* __restrict__ p0, const float* __restrict__ p1,
                float* __restrict__ sarr, float* __restrict__ sqarr,
                float* __restrict__ mxarr, float* __restrict__ mnarr) {
  int bt = blockIdx.x, c = threadIdx.x;
  size_t base = (size_t)bt * HWO * NC + c;
  float s = 0.f, sq = 0.f, mx = -3.4e38f, mn = 3.4e38f;
#pragma unroll 6
  for (int hw = 0; hw < HWO; ++hw) {
    size_t off = base + (size_t)hw * NC;
    float v = p0[off] + p1[off];
    s += v; sq += v * v;
    mx = fmaxf(mx, v); mn = fminf(mn, v);
  }
  int o = bt * NC + c;
  sarr[o] = s; sqarr[o] = sq; mxarr[o] = mx; mnarr[o] = mn;
}

// ---------------- 4b) BN finalize stage A: 32 blocks x 16 bt-rows ----------------
__global__ __launch_bounds__(384)
void bn_finA(const float* __restrict__ sarr, const float* __restrict__ sqarr,
             float* __restrict__ partA) {
  int c = threadIdx.x;
  int b0 = blockIdx.x * 16;
  float s = 0.f, sq = 0.f;
#pragma unroll
  for (int i = 0; i < 16; ++i) {
    s += sarr[(b0 + i) * NC + c];
    sq += sqarr[(b0 + i) * NC + c];
  }
  partA[blockIdx.x * 768 + c] = s;
  partA[blockIdx.x * 768 + 384 + c] = sq;
}

// ---------------- 5) LayerNorm over pooled features (bn_finB folded in: each block
// derives bnsc/bnsh from L2-resident partA — 64 extra hidden loads/thread) ----------------
__global__ __launch_bounds__(384)
void pool_ln(const float* __restrict__ sarr, const float* __restrict__ mxarr,
             const float* __restrict__ mnarr, const float* __restrict__ partA,
             const float* __restrict__ bn_g, const float* __restrict__ bn_b,
             const float* __restrict__ ln_g, const float* __restrict__ ln_b,
             float* __restrict__ y) {
  __shared__ float r1[6], r2[6], stats[2];
  int bt = blockIdx.x, c = threadIdx.x;
  float s = 0.f, sq = 0.f;
#pragma unroll
  for (int i = 0; i < 32; ++i) {
    s += partA[i * 768 + c];
    sq += partA[i * 768 + 384 + c];
  }
  float mean = s / (float)MCONV;
  float var = sq / (float)MCONV - mean * mean;
  float sc = bn_g[c] / sqrtf(var + 1e-5f);
  float sh = bn_b[c] - mean * sc;

  int o = bt * NC + c;
  float meanv = sarr[o] * (1.f / 36.f) * sc + sh;
  float mxv = (sc >= 0.f ? mxarr[o] : mnarr[o]) * sc + sh;
  float v1 = meanv + mxv;
  float v2 = meanv * meanv + mxv * mxv;
#pragma unroll
  for (int off = 32; off; off >>= 1) {
    v1 += __shfl_down(v1, off, 64);
    v2 += __shfl_down(v2, off, 64);
  }
  if ((c & 63) == 0) { r1[c >> 6] = v1; r2[c >> 6] = v2; }
  __syncthreads();
  if (c == 0) {
    float S1 = 0.f, S2 = 0.f;
#pragma unroll
    for (int i = 0; i < 6; ++i) { S1 += r1[i]; S2 += r2[i]; }
    float mu = S1 / (float)C2;
    float varl = S2 / (float)C2 - mu * mu;
    stats[0] = mu;
    stats[1] = 1.0f / sqrtf(varl + 1e-5f);
  }
  __syncthreads();
  float mu = stats[0], rstd = stats[1];
  y[(size_t)bt * C2 + c] = (meanv - mu) * rstd * ln_g[c] + ln_b[c];
  y[(size_t)bt * C2 + 384 + c] = (mxv - mu) * rstd * ln_g[384 + c] + ln_b[384 + c];
}

// ---------------- 6) small fp32 GEMM, 32x64 tiles (R10-measured win vs 64x64) ----------------
template <int GELU, int X2, int GM>
__global__ __launch_bounds__(256)
void gemm32(const float* __restrict__ A, const float* __restrict__ gmv,
            const float* __restrict__ Wm,
            const float* __restrict__ bias, float* __restrict__ Cm,
            int K, int N, float* __restrict__ gmout) {
  __shared__ float As[32][17];
  __shared__ float Bs[16][68];
  __shared__ float gmred[16][64];
  int tid = threadIdx.x;
  int tx = tid & 15, ty = tid >> 4;         // ty: 16 groups of 2 rows
  int m0 = blockIdx.y * 32, n0 = blockIdx.x * 64;
  int br = tid >> 4, bc = (tid & 15) * 4;
  float acc[2][4] = {};
  for (int kt = 0; kt < K; kt += 16) {
    if (tid < 128) {
      int ar = tid >> 2, ak = (tid & 3) * 4;
      int kcol = kt + ak;
      float4 av;
      if (X2 && kcol >= 384)
        av = *(const float4*)(gmv + ((m0 + ar) >> 4) * 384 + (kcol - 384));
      else
        av = *(const float4*)(A + (size_t)(m0 + ar) * K + kcol);
      As[ar][ak + 0] = av.x; As[ar][ak + 1] = av.y;
      As[ar][ak + 2] = av.z; As[ar][ak + 3] = av.w;
    }
    float4 bv = *(const float4*)(Wm + (size_t)(kt + br) * N + n0 + bc);
    Bs[br][bc + 0] = bv.x; Bs[br][bc + 1] = bv.y;
    Bs[br][bc + 2] = bv.z; Bs[br][bc + 3] = bv.w;
    __syncthreads();
#pragma unroll
    for (int kk = 0; kk < 16; ++kk) {
      float a0 = As[ty * 2 + 0][kk], a1 = As[ty * 2 + 1][kk];
      float b0 = Bs[kk][tx * 4 + 0], b1 = Bs[kk][tx * 4 + 1];
      float b2 = Bs[kk][tx * 4 + 2], b3 = Bs[kk][tx * 4 + 3];
      acc[0][0] += a0 * b0; acc[0][1] += a0 * b1; acc[0][2] += a0 * b2; acc[0][3] += a0 * b3;
      acc[1][0] += a1 * b0; acc[1][1] += a1 * b1; acc[1][2] += a1 * b2; acc[1][3] += a1 * b3;
    }
    __syncthreads();
  }
  float vout[2][4];
#pragma unroll
  for (int i = 0; i < 2; ++i) {
    int row = m0 + ty * 2 + i;
#pragma unroll
    for (int j = 0; j < 4; ++j) {
      int col = n0 + tx * 4 + j;
      float v = acc[i][j] + bias[col];
      if (GELU) v = 0.5f * v * (1.0f + erff(v * 0.70710678118654752f));
      vout[i][j] = v;
      Cm[(size_t)row * N + col] = v;
    }
  }
  if (GM && n0 >= 384) {
#pragma unroll
    for (int j = 0; j < 4; ++j)
      gmred[ty][tx * 4 + j] = vout[0][j] + vout[1][j];
    __syncthreads();
    if (tid < 128) {
      int b_l = tid >> 6, col = tid & 63;   // b_l: 0..1
      float g = 0.f;
#pragma unroll
      for (int i = 0; i < 8; ++i) g += gmred[b_l * 8 + i][col];
      gmout[(blockIdx.y * 2 + b_l) * 384 + (n0 - 384) + col] = g * (1.f / 16.f);
    }
  }
}

// ---------------- 9) score head: 4 sample-chunks of 250 per b (250/256 lanes active) ----------------
__global__ __launch_bounds__(256)
void score_head(const float* __restrict__ h2, const float* __restrict__ w3,
                const float* __restrict__ b3, const float* __restrict__ noise,
                unsigned* __restrict__ pcnt, float* __restrict__ out_inds) {
  int b = blockIdx.x >> 2, chunk = blockIdx.x & 3;
  int tid = threadIdx.x;
  int lane = tid & 63, wv = tid >> 6;
  __shared__ float sv[16], sn[16];
  __shared__ unsigned cnt[256];
  for (int t = wv; t < 16; t += 4) {
    const float* hr = h2 + ((size_t)b * 16 + t) * 192;
    float p = 0.f;
    for (int i = lane; i < 192; i += 64) p += hr[i] * w3[i];
#pragma unroll
    for (int off = 32; off; off >>= 1) p += __shfl_down(p, off, 64);
    if (lane == 0) sv[t] = p + b3[0];
  }
  cnt[tid] = 0;
  __syncthreads();
  if (tid == 0) {
    float mn = sv[0], mx = sv[0];
    for (int t = 1; t < 16; ++t) { mn = fminf(mn, sv[t]); mx = fmaxf(mx, sv[t]); }
    float inv = 1.0f / (mx - mn + 1e-5f);
    for (int t = 0; t < 16; ++t) sn[t] = (sv[t] - mn) * inv;
  }
  __syncthreads();
  if (chunk == 0 && tid < 16) {
    int t = tid, r = 0;
    for (int u = 0; u < 16; ++u)
      r += (sv[u] < sv[t]) || (sv[u] == sv[t] && u < t);
    out_inds[b * 16 + r] = (float)t;
  }
  if (tid < 250) {
    int s = chunk * 250 + tid;
    const float* nz = noise + ((size_t)b * NSAMP + s) * 16;
    float pert[16];
#pragma unroll
    for (int t = 0; t < 16; ++t) pert[t] = sn[t] + 0.05f * nz[t];
    unsigned tm = 0, bm2 = 0;
#pragma unroll
    for (int t = 0; t < 16; ++t) {
      int ct = 0, cb = 0;
#pragma unroll
      for (int u = 0; u < 16; ++u) {
        ct += (pert[u] > pert[t]) || (pert[u] == pert[t] && u < t);
        cb += (pert[u] < pert[t]) || (pert[u] == pert[t] && u < t);
      }
      if (ct < 8) tm |= 1u << t;
      if (cb < 8) bm2 |= 1u << t;
    }
    int j = 0, jb = 0;
#pragma unroll
    for (int t = 0; t < 16; ++t) {
      if (tm & (1u << t)) { if (j < 8) atomicAdd(&cnt[j * 16 + t], 1u); ++j; }
      if (bm2 & (1u << t)) { if (jb < 8) atomicAdd(&cnt[128 + jb * 16 + t], 1u); ++jb; }
    }
  }
  __syncthreads();
  pcnt[(size_t)(b * 4 + chunk) * 256 + tid] = cnt[tid];
}

// ---------------- 10) weighted gather of frames (float4), sums 4 count-chunks ----------------
__global__ __launch_bounds__(256)
void gather_k(const float* __restrict__ frames, const unsigned* __restrict__ pcnt,
              float* __restrict__ out) {
  int bid = blockIdx.x;             // 4 (b,c) pairs per block; same b (384%4==0)
  int tid = threadIdx.x;
  int b = (bid * 4) / NC;
  __shared__ float wt[256];
  {
    unsigned s = 0;
    const unsigned* pc = pcnt + (size_t)b * 4 * 256 + tid;
#pragma unroll
    for (int ch = 0; ch < 4; ++ch) s += pc[ch * 256];
    wt[tid] = (float)s / 1000.0f;
  }
  __syncthreads();
  if (tid >= 196) return;
  int cc = tid / 49, q = tid - cc * 49;
  int bc = bid * 4 + cc;
  const float4* src = (const float4*)(frames + (size_t)bc * NT * HWI) + q;
  float4 v[16];
#pragma unroll
  for (int t = 0; t < 16; ++t) v[t] = src[t * 49];
  float4* o1 = (float4*)(out + (size_t)bc * TOPK * HWI) + q;
  float4* o2 = (float4*)(out + OUT_TOPK_ELEMS + (size_t)bc * TOPK * HWI) + q;
#pragma unroll
  for (int k = 0; k < TOPK; ++k) {
    float4 st = {0.f, 0.f, 0.f, 0.f}, sb = {0.f, 0.f, 0.f, 0.f};
#pragma unroll
    for (int t = 0; t < 16; ++t) {
      float a = wt[k * 16 + t], bw = wt[128 + k * 16 + t];
      st.x += a * v[t].x; st.y += a * v[t].y; st.z += a * v[t].z; st.w += a * v[t].w;
      sb.x += bw * v[t].x; sb.y += bw * v[t].y; sb.z += bw * v[t].z; sb.w += bw * v[t].w;
    }
    o1[k * 49] = st;
    o2[k * 49] = sb;
  }
}

// ---------------- launcher ----------------
extern "C" void kernel_launch(void* const* d_in, const int* in_sizes, int n_in,
                              void* d_out, int out_size, void* d_ws, size_t ws_size,
                              hipStream_t stream) {
  const float* frames = (const float*)d_in[0];
  const float* noise  = (const float*)d_in[1];
  const float* conv_w = (const float*)d_in[2];
  const float* conv_b = (const float*)d_in[3];
  const float* bn_g   = (const float*)d_in[4];
  const float* bn_b   = (const float*)d_in[5];
  const float* ln_g   = (const float*)d_in[6];
  const float* ln_b   = (const float*)d_in[7];
  const float* lin_w  = (const float*)d_in[8];
  const float* lin_b  = (const float*)d_in[9];
  const float* w1     = (const float*)d_in[10];
  const float* b1     = (const float*)d_in[11];
  const float* w2     = (const float*)d_in[12];
  const float* b2     = (const float*)d_in[13];
  const float* w3     = (const float*)d_in[14];
  const float* b3     = (const float*)d_in[15];

  char* ws = (char*)d_ws;
  unsigned short* fhi = (unsigned short*)(ws + OFF_FHI);
  unsigned short* flo = (unsigned short*)(ws + OFF_FLO);
  unsigned short* whi = (unsigned short*)(ws + OFF_WHI);
  unsigned short* wlo = (unsigned short*)(ws + OFF_WLO);
  float* p0    = (float*)(ws + OFF_CONV);
  float* sarr  = (float*)(ws + OFF_SARR);
  float* sqarr = (float*)(ws + OFF_SQAR);
  float* mxarr = (float*)(ws + OFF_MXAR);
  float* mnarr = (float*)(ws + OFF_MNAR);
  float* y     = (float*)(ws + OFF_Y);
  float* x1    = (float*)(ws + OFF_X1);
  float* gm    = (float*)(ws + OFF_GM);
  float* h1    = (float*)(ws + OFF_H1);
  float* h2    = (float*)(ws + OFF_H2);
  unsigned* pcnt = (unsigned*)(ws + OFF_PCNT);
  float* partA = (float*)(ws + OFF_PARTA);
  float* out   = (float*)d_out;
  // p1 scratch lives in d_out (extent 7.1M floats < inds offset 38.5M);
  // gather_k overwrites it later on the same serial stream.
  float* p1    = out;

  split_all<<<3456, 256, 0, stream>>>(frames, conv_w, fhi, flo, whi, wlo);
  conv_gemm<<<864, 256, 0, stream>>>(fhi, flo, whi, wlo, conv_b, p0, p1);
  reduce_all<<<512, 384, 0, stream>>>(p0, p1, sarr, sqarr, mxarr, mnarr);
  bn_finA<<<32, 384, 0, stream>>>(sarr, sqarr, partA);
  pool_ln<<<512, 384, 0, stream>>>(sarr, mxarr, mnarr, partA, bn_g, bn_b, ln_g, ln_b, y);
  gemm32<1, 0, 1><<<dim3(12, 16), 256, 0, stream>>>(y, nullptr, lin_w, lin_b, x1, 768, 768, gm);
  gemm32<1, 1, 0><<<dim3(6, 16), 256, 0, stream>>>(x1, gm, w1, b1, h1, 768, 384, nullptr);
  gemm32<1, 0, 0><<<dim3(3, 16), 256, 0, stream>>>(h1, nullptr, w2, b2, h2, 384, 192, nullptr);
  score_head<<<128, 256, 0, stream>>>(h2, w3, b3, noise, pcnt, out + OUT_INDS_OFF);
  gather_k<<<3072, 256, 0, stream>>>(frames, pcnt, out);
}